// Round 6
// baseline (658.766 us; speedup 1.0000x reference)
//
#include <hip/hip_runtime.h>

#define EMBED 768
#define NH 12
#define HD 64
#define MEMN 64
#define BB 8
#define TT 1024
#define ROWS 8192
#define QKV_N 2304
#define QSZ 6291456           // B*T*C = B*NH*TT*HD (elements)

typedef short bf16x8_t __attribute__((ext_vector_type(8)));
typedef float f32x4_t __attribute__((ext_vector_type(4)));

__device__ __forceinline__ unsigned short f2b(float f){
    union { float f; unsigned int i; } v; v.f = f;
    unsigned int x = v.i;
    unsigned int r = x + 0x7fffu + ((x >> 16) & 1u);
    return (unsigned short)(r >> 16);
}

// async global->LDS, 16B per lane; lds base must be wave-uniform (lane*16 implicit)
__device__ __forceinline__ void gl16(const unsigned short* g, unsigned short* l){
    __builtin_amdgcn_global_load_lds(
        (const __attribute__((address_space(1))) void*)g,
        (__attribute__((address_space(3))) void*)l,
        16, 0, 0);
}

// ---------------- flat fp32 -> bf16 convert (8 elems/thread) ----------------
__global__ __launch_bounds__(256) void cvt_kernel(
    const float* __restrict__ in, unsigned short* __restrict__ out, int n)
{
    int i = (blockIdx.x * 256 + threadIdx.x) * 8;
    if (i >= n) return;
    float4 f0 = *(const float4*)&in[i];
    float4 f1 = *(const float4*)&in[i + 4];
    union { bf16x8_t v; unsigned short s[8]; } u;
    u.s[0] = f2b(f0.x); u.s[1] = f2b(f0.y); u.s[2] = f2b(f0.z); u.s[3] = f2b(f0.w);
    u.s[4] = f2b(f1.x); u.s[5] = f2b(f1.y); u.s[6] = f2b(f1.z); u.s[7] = f2b(f1.w);
    *(bf16x8_t*)&out[i] = u.v;
}

// ------------- fp32 [R][C] -> bf16 transposed [C][R] -------------
__global__ __launch_bounds__(256) void tcvt_kernel(
    const float* __restrict__ in, unsigned short* __restrict__ out, int R, int C)
{
    __shared__ unsigned short tile[32][33];
    int bc = blockIdx.x * 32, br = blockIdx.y * 32;
    int t = threadIdx.x;
    int lr = t >> 5, lc = t & 31;
    for (int i = 0; i < 4; i++) {
        int r = lr + i * 8;
        tile[r][lc] = f2b(in[(size_t)(br + r) * C + bc + lc]);
    }
    __syncthreads();
    for (int i = 0; i < 4; i++) {
        int r = lr + i * 8;
        out[(size_t)(bc + r) * R + br + lc] = tile[lc][r];
    }
}

// ---- m97-style 128x128 bf16 GEMM: A (MxK bf16), BT (NxK bf16), bias fp32 ----
// mode 0: QKV scatter  q (pre-scaled by log2e/8) -> dq [B,T,768];
//         k -> dkv [B,H,T,D]; v -> dkv+QSZ as TRANSPOSED [B,H,D,T]
// mode 1: fp32 row-major -> df
__global__ __launch_bounds__(256) void gemm_bt(
    const unsigned short* __restrict__ A,
    const unsigned short* __restrict__ BT,
    const float* __restrict__ bias,
    unsigned short* __restrict__ dq,
    unsigned short* __restrict__ dkv,
    float* __restrict__ df,
    int M, int N, int K, int mode)
{
    __shared__ unsigned short As[4096];   // 128 x 32, no pad (global_load_lds layout)
    __shared__ unsigned short Bs[4096];
    const int t = threadIdx.x;
    const int wave = t >> 6, lane = t & 63;
    const int ln = lane & 15, lq = lane >> 4;
    const int wm = (wave >> 1) * 64, wn = (wave & 1) * 64;
    const int bm = blockIdx.y * 128, bn = blockIdx.x * 128;

    f32x4_t acc[4][4];
    for (int i = 0; i < 4; i++)
        for (int j = 0; j < 4; j++) acc[i][j] = (f32x4_t)(0.f);

    const int srow = wave * 16 + (lane >> 2);
    const int scol = (lane & 3) * 8;
    unsigned short* a0 = &As[wave * 512];
    unsigned short* a1 = &As[2048 + wave * 512];
    unsigned short* b0 = &Bs[wave * 512];
    unsigned short* b1 = &Bs[2048 + wave * 512];
    const unsigned short* Ap = A + (size_t)(bm + srow) * K + scol;
    const unsigned short* Bp = BT + (size_t)(bn + srow) * K + scol;

    for (int k0 = 0; k0 < K; k0 += 32) {
        __syncthreads();
        gl16(Ap + k0, a0);
        gl16(Ap + (size_t)64 * K + k0, a1);
        gl16(Bp + k0, b0);
        gl16(Bp + (size_t)64 * K + k0, b1);
        __syncthreads();

        bf16x8_t af[4], bfr[4];
        for (int mt = 0; mt < 4; mt++)
            af[mt] = *(bf16x8_t*)&As[(wm + mt * 16 + ln) * 32 + lq * 8];
        for (int nt = 0; nt < 4; nt++)
            bfr[nt] = *(bf16x8_t*)&Bs[(wn + nt * 16 + ln) * 32 + lq * 8];
        for (int mt = 0; mt < 4; mt++)
            for (int nt = 0; nt < 4; nt++)
                acc[mt][nt] = __builtin_amdgcn_mfma_f32_16x16x32_bf16(
                    af[mt], bfr[nt], acc[mt][nt], 0, 0, 0);
    }

    const float QSCALE = 0.125f * 1.44269504088896340736f;  // folded softmax scale (exp2 domain)
    for (int nt = 0; nt < 4; nt++) {
        int c = bn + wn + nt * 16 + ln;
        float bv = bias[c];
        for (int mt = 0; mt < 4; mt++) {
            for (int r = 0; r < 4; r++) {
                int row = bm + wm + mt * 16 + lq * 4 + r;
                float val = acc[mt][nt][r] + bv;
                if (mode == 0) {
                    int bb = row >> 10, tt = row & 1023;
                    int s = c / 768; int rem = c - s * 768;
                    int h = rem >> 6, d = rem & 63;
                    if (s == 0) {
                        dq[(size_t)row * 768 + rem] = f2b(val * QSCALE);
                    } else if (s == 1) {
                        dkv[(((size_t)(bb * 12 + h) * 1024 + tt) << 6) + d] = f2b(val);
                    } else {
                        // v transposed: [B,H,D,T]
                        dkv[(size_t)QSZ + ((size_t)(bb * 12 + h) << 16) + (d << 10) + tt]
                            = f2b(val);
                    }
                } else {
                    df[(size_t)row * N + c] = val;
                }
            }
        }
    }
}

// ---- memory projection (tiny): writes mem_k [H,M,D] and mem_v [H,D,M] ----
__global__ __launch_bounds__(256) void memproj_kernel(
    const float* __restrict__ A,
    const float* __restrict__ B,
    const float* __restrict__ bias,
    unsigned short* __restrict__ dmem_k,
    unsigned short* __restrict__ dmem_v)
{
    __shared__ unsigned short As[64][40];
    __shared__ unsigned short Bs[64][40];   // transposed: Bs[n][k]
    int t = threadIdx.x;
    int wave = t >> 6, lane = t & 63;
    int ln = lane & 15, lq = lane >> 4;
    int bn = blockIdx.x * 64;
    const int K = EMBED, N = EMBED;

    f32x4_t acc[4];
    for (int i = 0; i < 4; i++) acc[i] = (f32x4_t)(0.f);

    int sm = t >> 2, sk = (t & 3) * 8;
    int bk = t >> 3, bn8 = (t & 7) * 8;

    for (int k0 = 0; k0 < K; k0 += 32) {
        __syncthreads();
        {
            float4 f0 = *(const float4*)&A[(size_t)sm * K + k0 + sk];
            float4 f1 = *(const float4*)&A[(size_t)sm * K + k0 + sk + 4];
            unsigned short* ap = &As[sm][sk];
            ap[0] = f2b(f0.x); ap[1] = f2b(f0.y); ap[2] = f2b(f0.z); ap[3] = f2b(f0.w);
            ap[4] = f2b(f1.x); ap[5] = f2b(f1.y); ap[6] = f2b(f1.z); ap[7] = f2b(f1.w);
        }
        {
            float4 g0 = *(const float4*)&B[(size_t)(k0 + bk) * N + bn + bn8];
            float4 g1 = *(const float4*)&B[(size_t)(k0 + bk) * N + bn + bn8 + 4];
            Bs[bn8 + 0][bk] = f2b(g0.x); Bs[bn8 + 1][bk] = f2b(g0.y);
            Bs[bn8 + 2][bk] = f2b(g0.z); Bs[bn8 + 3][bk] = f2b(g0.w);
            Bs[bn8 + 4][bk] = f2b(g1.x); Bs[bn8 + 5][bk] = f2b(g1.y);
            Bs[bn8 + 6][bk] = f2b(g1.z); Bs[bn8 + 7][bk] = f2b(g1.w);
        }
        __syncthreads();
        bf16x8_t a = *(bf16x8_t*)&As[wave * 16 + ln][lq * 8];
        for (int nt = 0; nt < 4; nt++) {
            bf16x8_t bf = *(bf16x8_t*)&Bs[nt * 16 + ln][lq * 8];
            acc[nt] = __builtin_amdgcn_mfma_f32_16x16x32_bf16(a, bf, acc[nt], 0, 0, 0);
        }
    }

    for (int nt = 0; nt < 4; nt++) {
        int c = bn + nt * 16 + ln;
        float bv = bias[c];
        for (int r = 0; r < 4; r++) {
            int row = wave * 16 + lq * 4 + r;   // m index 0..63
            int h = c >> 6, d = c & 63;
            unsigned short o = f2b(acc[nt][r] + bv);
            dmem_k[((h * 64 + row) << 6) + d] = o;   // [H,M,D]
            dmem_v[((h * 64 + d) << 6) + row] = o;   // [H,D,M]
        }
    }
}

// ---- flash attention, unnormalized exp2 (scale pre-folded into q), memory attention ----
// All staging via global_load_lds; V pre-transposed globally; Q frags hoisted; Ps aliases Qs.
__global__ __launch_bounds__(256) void attn_kernel(
    unsigned short* __restrict__ qio,           // [B,T,768] bf16, in/out (q pre-scaled)
    const unsigned short* __restrict__ k_ws,    // [B,H,T,D] bf16
    const unsigned short* __restrict__ vT_ws,   // [B,H,D,T] bf16 (transposed)
    const unsigned short* __restrict__ mem_k,   // [H,M,D]   bf16
    const unsigned short* __restrict__ mem_v)   // [H,D,M]   bf16
{
    __shared__ unsigned short Qs[4096];   // 64 x 64 unpadded (gl16 layout)
    __shared__ unsigned short Ks[4096];
    __shared__ unsigned short Vs[4096];   // rows = d, cols = key (from global V^T)
    unsigned short* Ps = Qs;              // Qs dead after aq hoist

    const int t = threadIdx.x;
    const int wave = t >> 6, lane = t & 63;
    const int ln = lane & 15, lq = lane >> 4;
    const int l8 = lane >> 3, c8 = (lane & 7) * 8;

    // XCD swizzle: all 16 q-tiles of one (b,h) land on one XCD -> K/V stays in its L2
    int bid = blockIdx.x;
    int xcd = bid & 7, rest = bid >> 3;
    int bh = xcd * 12 + (rest >> 4);   // 0..95 == b*NH + h
    int qt = rest & 15;
    int b = bh / 12, h = bh - b * 12;

    unsigned short* qp = qio + ((size_t)(b * TT + qt * 64)) * 768 + h * 64;
    const unsigned short* kp = k_ws + (size_t)bh * TT * 64;
    const unsigned short* vp = vT_ws + ((size_t)bh << 16);       // [d][t]
    const unsigned short* mkp = mem_k + h * 4096;
    const unsigned short* mvp = mem_v + h * 4096;

    // stage Q (rows wave*8.. / +32), then hoist the wave's A-fragments
    {
        const unsigned short* qg = qp + (size_t)(wave * 8 + l8) * 768 + c8;
        gl16(qg, &Qs[wave * 512]);
        gl16(qg + (size_t)32 * 768, &Qs[2048 + wave * 512]);
    }
    __syncthreads();
    bf16x8_t aq0 = *(bf16x8_t*)&Qs[(wave * 16 + ln) * 64 + lq * 8];
    bf16x8_t aq1 = *(bf16x8_t*)&Qs[(wave * 16 + ln) * 64 + 32 + lq * 8];

    // staging addresses (lane-resolved once)
    const unsigned short* kg = kp + (wave * 8 + l8) * 64 + c8;
    const unsigned short* vg = vp + (size_t)(wave * 8 + l8) * 1024 + c8;
    unsigned short* ksd0 = &Ks[wave * 512];
    unsigned short* ksd1 = &Ks[2048 + wave * 512];
    unsigned short* vsd0 = &Vs[wave * 512];
    unsigned short* vsd1 = &Vs[2048 + wave * 512];

    float lsum[4] = {0.f, 0.f, 0.f, 0.f};
    f32x4_t accO[4];
    for (int nt = 0; nt < 4; nt++) accO[nt] = (f32x4_t)(0.f);

    for (int kt = 0; kt < 16; kt++) {
        __syncthreads();                       // prev Ks/Vs/Ps reads done (iter0: aq reads done)
        gl16(kg + kt * 4096, ksd0);
        gl16(kg + kt * 4096 + 2048, ksd1);
        gl16(vg + kt * 64, vsd0);
        gl16(vg + (size_t)32 * 1024 + kt * 64, vsd1);
        __syncthreads();                       // drains vmcnt -> tiles visible

        f32x4_t s[4];
        for (int nt = 0; nt < 4; nt++) s[nt] = (f32x4_t)(0.f);
        for (int nt = 0; nt < 4; nt++)
            s[nt] = __builtin_amdgcn_mfma_f32_16x16x32_bf16(
                aq0, *(bf16x8_t*)&Ks[(nt * 16 + ln) * 64 + lq * 8], s[nt], 0, 0, 0);
        for (int nt = 0; nt < 4; nt++)
            s[nt] = __builtin_amdgcn_mfma_f32_16x16x32_bf16(
                aq1, *(bf16x8_t*)&Ks[(nt * 16 + ln) * 64 + 32 + lq * 8], s[nt], 0, 0, 0);

        for (int nt = 0; nt < 4; nt++) {
            for (int r = 0; r < 4; r++) {
                float p = exp2f(s[nt][r]);
                lsum[r] += p;
                Ps[(wave * 16 + lq * 4 + r) * 64 + nt * 16 + ln] = f2b(p);
            }
        }
        // Ps slab is wave-private: no barrier needed
        for (int kk = 0; kk < 2; kk++) {
            bf16x8_t a = *(bf16x8_t*)&Ps[(wave * 16 + ln) * 64 + kk * 32 + lq * 8];
            for (int nt = 0; nt < 4; nt++) {
                bf16x8_t bf = *(bf16x8_t*)&Vs[(nt * 16 + ln) * 64 + kk * 32 + lq * 8];
                accO[nt] = __builtin_amdgcn_mfma_f32_16x16x32_bf16(a, bf, accO[nt], 0, 0, 0);
            }
        }
    }

    // memory attention: independent unnormalized softmax over 64 projected-memory keys
    __syncthreads();
    {
        const unsigned short* mk = mkp + (wave * 8 + l8) * 64 + c8;
        const unsigned short* mv = mvp + (wave * 8 + l8) * 64 + c8;
        gl16(mk, ksd0);
        gl16(mk + 2048, ksd1);
        gl16(mv, vsd0);
        gl16(mv + 2048, vsd1);
    }
    __syncthreads();

    f32x4_t s2[4];
    for (int nt = 0; nt < 4; nt++) s2[nt] = (f32x4_t)(0.f);
    for (int nt = 0; nt < 4; nt++)
        s2[nt] = __builtin_amdgcn_mfma_f32_16x16x32_bf16(
            aq0, *(bf16x8_t*)&Ks[(nt * 16 + ln) * 64 + lq * 8], s2[nt], 0, 0, 0);
    for (int nt = 0; nt < 4; nt++)
        s2[nt] = __builtin_amdgcn_mfma_f32_16x16x32_bf16(
            aq1, *(bf16x8_t*)&Ks[(nt * 16 + ln) * 64 + 32 + lq * 8], s2[nt], 0, 0, 0);

    float l2[4] = {0.f, 0.f, 0.f, 0.f};
    for (int nt = 0; nt < 4; nt++) {
        for (int r = 0; r < 4; r++) {
            float p = exp2f(s2[nt][r]);
            l2[r] += p;
            Ps[(wave * 16 + lq * 4 + r) * 64 + nt * 16 + ln] = f2b(p);
        }
    }
    f32x4_t accM[4];
    for (int nt = 0; nt < 4; nt++) accM[nt] = (f32x4_t)(0.f);
    for (int kk = 0; kk < 2; kk++) {
        bf16x8_t a = *(bf16x8_t*)&Ps[(wave * 16 + ln) * 64 + kk * 32 + lq * 8];
        for (int nt = 0; nt < 4; nt++) {
            bf16x8_t bf = *(bf16x8_t*)&Vs[(nt * 16 + ln) * 64 + kk * 32 + lq * 8];
            accM[nt] = __builtin_amdgcn_mfma_f32_16x16x32_bf16(a, bf, accM[nt], 0, 0, 0);
        }
    }

    // single deferred cross-lane reduction of the denominators
    float inv[4], inv2[4];
    for (int r = 0; r < 4; r++) {
        float a = lsum[r], c = l2[r];
        a += __shfl_xor(a, 1); a += __shfl_xor(a, 2);
        a += __shfl_xor(a, 4); a += __shfl_xor(a, 8);
        c += __shfl_xor(c, 1); c += __shfl_xor(c, 2);
        c += __shfl_xor(c, 4); c += __shfl_xor(c, 8);
        inv[r] = 1.f / a;
        inv2[r] = 1.f / c;
    }

    // in-place write over this block's own q slice (staged to LDS at entry)
    for (int nt = 0; nt < 4; nt++) {
        for (int r = 0; r < 4; r++) {
            int lrow = wave * 16 + lq * 4 + r;
            int lcol = nt * 16 + ln;
            float val = accO[nt][r] * inv[r] + accM[nt][r] * inv2[r];
            qp[(size_t)lrow * 768 + lcol] = f2b(val);
        }
    }
}

// ---------------- host ----------------
extern "C" void kernel_launch(void* const* d_in, const int* in_sizes, int n_in,
                              void* d_out, int out_size, void* d_ws, size_t ws_size,
                              hipStream_t stream) {
    const float* x      = (const float*)d_in[0];
    const float* w_qkv  = (const float*)d_in[1];
    const float* b_qkv  = (const float*)d_in[2];
    const float* w_out  = (const float*)d_in[3];
    const float* b_out  = (const float*)d_in[4];
    const float* w_mem  = (const float*)d_in[5];
    const float* b_mem  = (const float*)d_in[6];
    const float* memory = (const float*)d_in[7];

    unsigned short* ws = (unsigned short*)d_ws;
    unsigned short* q_ws   = ws;                         // [B,T,C] bf16; attn writes in-place
    unsigned short* k_ws   = ws + (size_t)QSZ;           // [B,H,T,D]; v^T follows at +QSZ
    unsigned short* woutT  = ws + 3 * (size_t)QSZ;       // [768][768] bf16 (N x K)
    unsigned short* mem_k  = woutT + (size_t)EMBED * EMBED;  // [H,M,D] bf16
    unsigned short* mem_v  = mem_k + (size_t)NH * MEMN * HD; // [H,D,M] bf16

    // x_bf16 + wqkvT park in d_out (dead before final GEMM overwrites d_out)
    unsigned short* xb    = (unsigned short*)d_out;      // [8192][768] bf16
    unsigned short* wqkvT = xb + (size_t)QSZ;            // [2304][768] bf16

    // 1) conversions
    cvt_kernel<<<QSZ / 2048, 256, 0, stream>>>(x, xb, QSZ);
    tcvt_kernel<<<dim3(QKV_N / 32, EMBED / 32), 256, 0, stream>>>(w_qkv, wqkvT, EMBED, QKV_N);
    tcvt_kernel<<<dim3(EMBED / 32, EMBED / 32), 256, 0, stream>>>(w_out, woutT, EMBED, EMBED);

    // 2) memory projection -> mem_k [H,M,D] + mem_v [H,D,M]
    memproj_kernel<<<dim3(EMBED / 64, 1), 256, 0, stream>>>(memory, w_mem, b_mem, mem_k, mem_v);

    // 3) QKV projection: q (pre-scaled) -> q_ws; k -> [B,H,T,D]; v -> [B,H,D,T]
    gemm_bt<<<dim3(QKV_N / 128, ROWS / 128), 256, 0, stream>>>(
        xb, wqkvT, b_qkv, q_ws, k_ws, nullptr, ROWS, QKV_N, EMBED, 0);

    // 4) attention (local flash + memory), in-place over q_ws; XCD-swizzled flat grid
    attn_kernel<<<16 * NH * BB, 256, 0, stream>>>(
        q_ws, k_ws, k_ws + (size_t)QSZ, mem_k, mem_v);

    // 5) output projection: q_ws(bf16) @ w_out + b_out -> d_out fp32
    gemm_bt<<<dim3(EMBED / 128, ROWS / 128), 256, 0, stream>>>(
        q_ws, woutT, b_out, nullptr, nullptr, (float*)d_out, ROWS, EMBED, EMBED, 1);
}

// Round 7
// 312.029 us; speedup vs baseline: 2.1112x; 2.1112x over previous
//
#include <hip/hip_runtime.h>

#define EMBED 768
#define NH 12
#define HD 64
#define MEMN 64
#define BB 8
#define TT 1024
#define ROWS 8192
#define QKV_N 2304
#define QSZ 6291456           // B*T*C = B*NH*TT*HD (elements)

typedef short bf16x8_t __attribute__((ext_vector_type(8)));
typedef float f32x4_t __attribute__((ext_vector_type(4)));

__device__ __forceinline__ unsigned short f2b(float f){
    union { float f; unsigned int i; } v; v.f = f;
    unsigned int x = v.i;
    unsigned int r = x + 0x7fffu + ((x >> 16) & 1u);
    return (unsigned short)(r >> 16);
}

// async global->LDS, 16B per lane; lds base must be wave-uniform (lane*16 implicit)
__device__ __forceinline__ void gl16(const unsigned short* g, unsigned short* l){
    __builtin_amdgcn_global_load_lds(
        (const __attribute__((address_space(1))) void*)g,
        (__attribute__((address_space(3))) void*)l,
        16, 0, 0);
}

// ---------------- flat fp32 -> bf16 convert (8 elems/thread) ----------------
__global__ __launch_bounds__(256) void cvt_kernel(
    const float* __restrict__ in, unsigned short* __restrict__ out, int n)
{
    int i = (blockIdx.x * 256 + threadIdx.x) * 8;
    if (i >= n) return;
    float4 f0 = *(const float4*)&in[i];
    float4 f1 = *(const float4*)&in[i + 4];
    union { bf16x8_t v; unsigned short s[8]; } u;
    u.s[0] = f2b(f0.x); u.s[1] = f2b(f0.y); u.s[2] = f2b(f0.z); u.s[3] = f2b(f0.w);
    u.s[4] = f2b(f1.x); u.s[5] = f2b(f1.y); u.s[6] = f2b(f1.z); u.s[7] = f2b(f1.w);
    *(bf16x8_t*)&out[i] = u.v;
}

// ------------- fp32 [R][C] -> bf16 transposed [C][R] -------------
__global__ __launch_bounds__(256) void tcvt_kernel(
    const float* __restrict__ in, unsigned short* __restrict__ out, int R, int C)
{
    __shared__ unsigned short tile[32][33];
    int bc = blockIdx.x * 32, br = blockIdx.y * 32;
    int t = threadIdx.x;
    int lr = t >> 5, lc = t & 31;
    for (int i = 0; i < 4; i++) {
        int r = lr + i * 8;
        tile[r][lc] = f2b(in[(size_t)(br + r) * C + bc + lc]);
    }
    __syncthreads();
    for (int i = 0; i < 4; i++) {
        int r = lr + i * 8;
        out[(size_t)(bc + r) * R + br + lc] = tile[lc][r];
    }
}

// ---- bf16 [BH][T][D] -> [BH][D][T] transpose, coalesced both sides ----
// NOTE: do NOT transpose in a GEMM epilogue with 2B lane-strided stores —
// round 6 measured 44x HBM write amplification (WRITE_SIZE 38MB -> 1.67GB).
__global__ __launch_bounds__(256) void vtrans_kernel(
    const unsigned short* __restrict__ in, unsigned short* __restrict__ out)
{
    __shared__ unsigned short tile[64][72];   // row stride 144B = 9*16 -> b128-aligned
    int t0 = blockIdx.x * 64;
    int bh = blockIdx.y;
    const unsigned short* ip = in + ((size_t)bh * TT + t0) * 64;
    unsigned short* op = out + ((size_t)bh * 64) * TT + t0;
    int t = threadIdx.x;
    for (int i = 0; i < 2; i++) {
        int idx = i * 256 + t;
        int r = idx >> 3, c8 = (idx & 7) * 8;           // r = t-row, c8 = d
        *(bf16x8_t*)&tile[r][c8] = *(const bf16x8_t*)&ip[(size_t)r * 64 + c8];
    }
    __syncthreads();
    for (int i = 0; i < 2; i++) {
        int idx = i * 256 + t;
        int d = idx >> 3, tc8 = (idx & 7) * 8;          // d = out row, tc8 = t offset
        union { bf16x8_t v; unsigned short s[8]; } u;
        for (int j = 0; j < 8; j++) u.s[j] = tile[tc8 + j][d];
        *(bf16x8_t*)&op[(size_t)d * TT + tc8] = u.v;
    }
}

// ---- m97-style 128x128 bf16 GEMM: A (MxK bf16), BT (NxK bf16), bias fp32 ----
// mode 0: QKV scatter  q (pre-scaled by log2e/8) -> dq [B,T,768];
//         k -> dkv [B,H,T,D]; v -> dkv+QSZ [B,H,T,D] (coalesced; transposed later)
// mode 1: fp32 row-major -> df
__global__ __launch_bounds__(256) void gemm_bt(
    const unsigned short* __restrict__ A,
    const unsigned short* __restrict__ BT,
    const float* __restrict__ bias,
    unsigned short* __restrict__ dq,
    unsigned short* __restrict__ dkv,
    float* __restrict__ df,
    int M, int N, int K, int mode)
{
    __shared__ unsigned short As[4096];   // 128 x 32, no pad (global_load_lds layout)
    __shared__ unsigned short Bs[4096];
    const int t = threadIdx.x;
    const int wave = t >> 6, lane = t & 63;
    const int ln = lane & 15, lq = lane >> 4;
    const int wm = (wave >> 1) * 64, wn = (wave & 1) * 64;
    const int bm = blockIdx.y * 128, bn = blockIdx.x * 128;

    f32x4_t acc[4][4];
    for (int i = 0; i < 4; i++)
        for (int j = 0; j < 4; j++) acc[i][j] = (f32x4_t)(0.f);

    const int srow = wave * 16 + (lane >> 2);
    const int scol = (lane & 3) * 8;
    unsigned short* a0 = &As[wave * 512];
    unsigned short* a1 = &As[2048 + wave * 512];
    unsigned short* b0 = &Bs[wave * 512];
    unsigned short* b1 = &Bs[2048 + wave * 512];
    const unsigned short* Ap = A + (size_t)(bm + srow) * K + scol;
    const unsigned short* Bp = BT + (size_t)(bn + srow) * K + scol;

    for (int k0 = 0; k0 < K; k0 += 32) {
        __syncthreads();
        gl16(Ap + k0, a0);
        gl16(Ap + (size_t)64 * K + k0, a1);
        gl16(Bp + k0, b0);
        gl16(Bp + (size_t)64 * K + k0, b1);
        __syncthreads();

        bf16x8_t af[4], bfr[4];
        for (int mt = 0; mt < 4; mt++)
            af[mt] = *(bf16x8_t*)&As[(wm + mt * 16 + ln) * 32 + lq * 8];
        for (int nt = 0; nt < 4; nt++)
            bfr[nt] = *(bf16x8_t*)&Bs[(wn + nt * 16 + ln) * 32 + lq * 8];
        for (int mt = 0; mt < 4; mt++)
            for (int nt = 0; nt < 4; nt++)
                acc[mt][nt] = __builtin_amdgcn_mfma_f32_16x16x32_bf16(
                    af[mt], bfr[nt], acc[mt][nt], 0, 0, 0);
    }

    const float QSCALE = 0.125f * 1.44269504088896340736f;  // folded softmax scale (exp2 domain)
    for (int nt = 0; nt < 4; nt++) {
        int c = bn + wn + nt * 16 + ln;
        float bv = bias[c];
        for (int mt = 0; mt < 4; mt++) {
            for (int r = 0; r < 4; r++) {
                int row = bm + wm + mt * 16 + lq * 4 + r;
                float val = acc[mt][nt][r] + bv;
                if (mode == 0) {
                    int bb = row >> 10, tt = row & 1023;
                    int s = c / 768; int rem = c - s * 768;
                    int h = rem >> 6, d = rem & 63;
                    if (s == 0) {
                        dq[(size_t)row * 768 + rem] = f2b(val * QSCALE);
                    } else {
                        dkv[(size_t)(s - 1) * QSZ +
                            (((size_t)(bb * 12 + h) * 1024 + tt) << 6) + d] = f2b(val);
                    }
                } else {
                    df[(size_t)row * N + c] = val;
                }
            }
        }
    }
}

// ---- memory projection (tiny): writes mem_k [H,M,D] and mem_v [H,D,M] ----
__global__ __launch_bounds__(256) void memproj_kernel(
    const float* __restrict__ A,
    const float* __restrict__ B,
    const float* __restrict__ bias,
    unsigned short* __restrict__ dmem_k,
    unsigned short* __restrict__ dmem_v)
{
    __shared__ unsigned short As[64][40];
    __shared__ unsigned short Bs[64][40];   // transposed: Bs[n][k]
    int t = threadIdx.x;
    int wave = t >> 6, lane = t & 63;
    int ln = lane & 15, lq = lane >> 4;
    int bn = blockIdx.x * 64;
    const int K = EMBED, N = EMBED;

    f32x4_t acc[4];
    for (int i = 0; i < 4; i++) acc[i] = (f32x4_t)(0.f);

    int sm = t >> 2, sk = (t & 3) * 8;
    int bk = t >> 3, bn8 = (t & 7) * 8;

    for (int k0 = 0; k0 < K; k0 += 32) {
        __syncthreads();
        {
            float4 f0 = *(const float4*)&A[(size_t)sm * K + k0 + sk];
            float4 f1 = *(const float4*)&A[(size_t)sm * K + k0 + sk + 4];
            unsigned short* ap = &As[sm][sk];
            ap[0] = f2b(f0.x); ap[1] = f2b(f0.y); ap[2] = f2b(f0.z); ap[3] = f2b(f0.w);
            ap[4] = f2b(f1.x); ap[5] = f2b(f1.y); ap[6] = f2b(f1.z); ap[7] = f2b(f1.w);
        }
        {
            float4 g0 = *(const float4*)&B[(size_t)(k0 + bk) * N + bn + bn8];
            float4 g1 = *(const float4*)&B[(size_t)(k0 + bk) * N + bn + bn8 + 4];
            Bs[bn8 + 0][bk] = f2b(g0.x); Bs[bn8 + 1][bk] = f2b(g0.y);
            Bs[bn8 + 2][bk] = f2b(g0.z); Bs[bn8 + 3][bk] = f2b(g0.w);
            Bs[bn8 + 4][bk] = f2b(g1.x); Bs[bn8 + 5][bk] = f2b(g1.y);
            Bs[bn8 + 6][bk] = f2b(g1.z); Bs[bn8 + 7][bk] = f2b(g1.w);
        }
        __syncthreads();
        bf16x8_t a = *(bf16x8_t*)&As[wave * 16 + ln][lq * 8];
        for (int nt = 0; nt < 4; nt++) {
            bf16x8_t bf = *(bf16x8_t*)&Bs[nt * 16 + ln][lq * 8];
            acc[nt] = __builtin_amdgcn_mfma_f32_16x16x32_bf16(a, bf, acc[nt], 0, 0, 0);
        }
    }

    for (int nt = 0; nt < 4; nt++) {
        int c = bn + nt * 16 + ln;
        float bv = bias[c];
        for (int r = 0; r < 4; r++) {
            int row = wave * 16 + lq * 4 + r;   // m index 0..63
            int h = c >> 6, d = c & 63;
            unsigned short o = f2b(acc[nt][r] + bv);
            dmem_k[((h * 64 + row) << 6) + d] = o;   // [H,M,D]
            dmem_v[((h * 64 + d) << 6) + row] = o;   // [H,D,M] (49K elems: amp harmless)
        }
    }
}

// ---- flash attention, unnormalized exp2 (scale pre-folded into q), memory attention ----
// All staging via global_load_lds; V pre-transposed globally; Q frags hoisted; Ps aliases Qs.
__global__ __launch_bounds__(256) void attn_kernel(
    unsigned short* __restrict__ qio,           // [B,T,768] bf16, in/out (q pre-scaled)
    const unsigned short* __restrict__ k_ws,    // [B,H,T,D] bf16
    const unsigned short* __restrict__ vT_ws,   // [B,H,D,T] bf16 (transposed)
    const unsigned short* __restrict__ mem_k,   // [H,M,D]   bf16
    const unsigned short* __restrict__ mem_v)   // [H,D,M]   bf16
{
    __shared__ unsigned short Qs[4096];   // 64 x 64 unpadded (gl16 layout)
    __shared__ unsigned short Ks[4096];
    __shared__ unsigned short Vs[4096];   // rows = d, cols = key (from global V^T)
    unsigned short* Ps = Qs;              // Qs dead after aq hoist

    const int t = threadIdx.x;
    const int wave = t >> 6, lane = t & 63;
    const int ln = lane & 15, lq = lane >> 4;
    const int l8 = lane >> 3, c8 = (lane & 7) * 8;

    // XCD swizzle: all 16 q-tiles of one (b,h) land on one XCD -> K/V stays in its L2
    int bid = blockIdx.x;
    int xcd = bid & 7, rest = bid >> 3;
    int bh = xcd * 12 + (rest >> 4);   // 0..95 == b*NH + h
    int qt = rest & 15;
    int b = bh / 12, h = bh - b * 12;

    unsigned short* qp = qio + ((size_t)(b * TT + qt * 64)) * 768 + h * 64;
    const unsigned short* kp = k_ws + (size_t)bh * TT * 64;
    const unsigned short* vp = vT_ws + ((size_t)bh << 16);       // [d][t]
    const unsigned short* mkp = mem_k + h * 4096;
    const unsigned short* mvp = mem_v + h * 4096;

    // stage Q (rows wave*8.. / +32), then hoist the wave's A-fragments
    {
        const unsigned short* qg = qp + (size_t)(wave * 8 + l8) * 768 + c8;
        gl16(qg, &Qs[wave * 512]);
        gl16(qg + (size_t)32 * 768, &Qs[2048 + wave * 512]);
    }
    __syncthreads();
    bf16x8_t aq0 = *(bf16x8_t*)&Qs[(wave * 16 + ln) * 64 + lq * 8];
    bf16x8_t aq1 = *(bf16x8_t*)&Qs[(wave * 16 + ln) * 64 + 32 + lq * 8];

    // staging addresses (lane-resolved once)
    const unsigned short* kg = kp + (wave * 8 + l8) * 64 + c8;
    const unsigned short* vg = vp + (size_t)(wave * 8 + l8) * 1024 + c8;
    unsigned short* ksd0 = &Ks[wave * 512];
    unsigned short* ksd1 = &Ks[2048 + wave * 512];
    unsigned short* vsd0 = &Vs[wave * 512];
    unsigned short* vsd1 = &Vs[2048 + wave * 512];

    float lsum[4] = {0.f, 0.f, 0.f, 0.f};
    f32x4_t accO[4];
    for (int nt = 0; nt < 4; nt++) accO[nt] = (f32x4_t)(0.f);

    for (int kt = 0; kt < 16; kt++) {
        __syncthreads();                       // prev Ks/Vs/Ps reads done (iter0: aq reads done)
        gl16(kg + kt * 4096, ksd0);
        gl16(kg + kt * 4096 + 2048, ksd1);
        gl16(vg + kt * 64, vsd0);
        gl16(vg + (size_t)32 * 1024 + kt * 64, vsd1);
        __syncthreads();                       // drains vmcnt -> tiles visible

        f32x4_t s[4];
        for (int nt = 0; nt < 4; nt++) s[nt] = (f32x4_t)(0.f);
        for (int nt = 0; nt < 4; nt++)
            s[nt] = __builtin_amdgcn_mfma_f32_16x16x32_bf16(
                aq0, *(bf16x8_t*)&Ks[(nt * 16 + ln) * 64 + lq * 8], s[nt], 0, 0, 0);
        for (int nt = 0; nt < 4; nt++)
            s[nt] = __builtin_amdgcn_mfma_f32_16x16x32_bf16(
                aq1, *(bf16x8_t*)&Ks[(nt * 16 + ln) * 64 + 32 + lq * 8], s[nt], 0, 0, 0);

        for (int nt = 0; nt < 4; nt++) {
            for (int r = 0; r < 4; r++) {
                float p = exp2f(s[nt][r]);
                lsum[r] += p;
                Ps[(wave * 16 + lq * 4 + r) * 64 + nt * 16 + ln] = f2b(p);
            }
        }
        // Ps slab is wave-private: no barrier needed
        for (int kk = 0; kk < 2; kk++) {
            bf16x8_t a = *(bf16x8_t*)&Ps[(wave * 16 + ln) * 64 + kk * 32 + lq * 8];
            for (int nt = 0; nt < 4; nt++) {
                bf16x8_t bf = *(bf16x8_t*)&Vs[(nt * 16 + ln) * 64 + kk * 32 + lq * 8];
                accO[nt] = __builtin_amdgcn_mfma_f32_16x16x32_bf16(a, bf, accO[nt], 0, 0, 0);
            }
        }
    }

    // memory attention: independent unnormalized softmax over 64 projected-memory keys
    __syncthreads();
    {
        const unsigned short* mk = mkp + (wave * 8 + l8) * 64 + c8;
        const unsigned short* mv = mvp + (wave * 8 + l8) * 64 + c8;
        gl16(mk, ksd0);
        gl16(mk + 2048, ksd1);
        gl16(mv, vsd0);
        gl16(mv + 2048, vsd1);
    }
    __syncthreads();

    f32x4_t s2[4];
    for (int nt = 0; nt < 4; nt++) s2[nt] = (f32x4_t)(0.f);
    for (int nt = 0; nt < 4; nt++)
        s2[nt] = __builtin_amdgcn_mfma_f32_16x16x32_bf16(
            aq0, *(bf16x8_t*)&Ks[(nt * 16 + ln) * 64 + lq * 8], s2[nt], 0, 0, 0);
    for (int nt = 0; nt < 4; nt++)
        s2[nt] = __builtin_amdgcn_mfma_f32_16x16x32_bf16(
            aq1, *(bf16x8_t*)&Ks[(nt * 16 + ln) * 64 + 32 + lq * 8], s2[nt], 0, 0, 0);

    float l2[4] = {0.f, 0.f, 0.f, 0.f};
    for (int nt = 0; nt < 4; nt++) {
        for (int r = 0; r < 4; r++) {
            float p = exp2f(s2[nt][r]);
            l2[r] += p;
            Ps[(wave * 16 + lq * 4 + r) * 64 + nt * 16 + ln] = f2b(p);
        }
    }
    f32x4_t accM[4];
    for (int nt = 0; nt < 4; nt++) accM[nt] = (f32x4_t)(0.f);
    for (int kk = 0; kk < 2; kk++) {
        bf16x8_t a = *(bf16x8_t*)&Ps[(wave * 16 + ln) * 64 + kk * 32 + lq * 8];
        for (int nt = 0; nt < 4; nt++) {
            bf16x8_t bf = *(bf16x8_t*)&Vs[(nt * 16 + ln) * 64 + kk * 32 + lq * 8];
            accM[nt] = __builtin_amdgcn_mfma_f32_16x16x32_bf16(a, bf, accM[nt], 0, 0, 0);
        }
    }

    // single deferred cross-lane reduction of the denominators
    float inv[4], inv2[4];
    for (int r = 0; r < 4; r++) {
        float a = lsum[r], c = l2[r];
        a += __shfl_xor(a, 1); a += __shfl_xor(a, 2);
        a += __shfl_xor(a, 4); a += __shfl_xor(a, 8);
        c += __shfl_xor(c, 1); c += __shfl_xor(c, 2);
        c += __shfl_xor(c, 4); c += __shfl_xor(c, 8);
        inv[r] = 1.f / a;
        inv2[r] = 1.f / c;
    }

    // in-place write over this block's own q slice (staged to LDS at entry)
    for (int nt = 0; nt < 4; nt++) {
        for (int r = 0; r < 4; r++) {
            int lrow = wave * 16 + lq * 4 + r;
            int lcol = nt * 16 + ln;
            float val = accO[nt][r] * inv[r] + accM[nt][r] * inv2[r];
            qp[(size_t)lrow * 768 + lcol] = f2b(val);
        }
    }
}

// ---------------- host ----------------
extern "C" void kernel_launch(void* const* d_in, const int* in_sizes, int n_in,
                              void* d_out, int out_size, void* d_ws, size_t ws_size,
                              hipStream_t stream) {
    const float* x      = (const float*)d_in[0];
    const float* w_qkv  = (const float*)d_in[1];
    const float* b_qkv  = (const float*)d_in[2];
    const float* w_out  = (const float*)d_in[3];
    const float* b_out  = (const float*)d_in[4];
    const float* w_mem  = (const float*)d_in[5];
    const float* b_mem  = (const float*)d_in[6];
    const float* memory = (const float*)d_in[7];

    unsigned short* ws = (unsigned short*)d_ws;
    unsigned short* q_ws   = ws;                         // [B,T,C] bf16; attn writes in-place
    unsigned short* k_ws   = ws + (size_t)QSZ;           // [B,H,T,D]; v ([B,H,T,D]) at +QSZ
    unsigned short* woutT  = ws + 3 * (size_t)QSZ;       // [768][768] bf16 (N x K)
    unsigned short* mem_k  = woutT + (size_t)EMBED * EMBED;  // [H,M,D] bf16
    unsigned short* mem_v  = mem_k + (size_t)NH * MEMN * HD; // [H,D,M] bf16

    // d_out (12.58M u16 slots) multi-use: xb + wqkvT live until QKV gemm;
    // then vT reuses xb's slot; out-proj finally overwrites everything with fp32.
    unsigned short* xb    = (unsigned short*)d_out;      // [8192][768] bf16
    unsigned short* wqkvT = xb + (size_t)QSZ;            // [2304][768] bf16
    unsigned short* vT    = (unsigned short*)d_out;      // [B,H,D,T] bf16 (after QKV gemm)

    // 1) conversions
    cvt_kernel<<<QSZ / 2048, 256, 0, stream>>>(x, xb, QSZ);
    tcvt_kernel<<<dim3(QKV_N / 32, EMBED / 32), 256, 0, stream>>>(w_qkv, wqkvT, EMBED, QKV_N);
    tcvt_kernel<<<dim3(EMBED / 32, EMBED / 32), 256, 0, stream>>>(w_out, woutT, EMBED, EMBED);

    // 2) memory projection -> mem_k [H,M,D] + mem_v [H,D,M]
    memproj_kernel<<<dim3(EMBED / 64, 1), 256, 0, stream>>>(memory, w_mem, b_mem, mem_k, mem_v);

    // 3) QKV projection: q (pre-scaled) -> q_ws; k,v -> [B,H,T,D] (coalesced stores)
    gemm_bt<<<dim3(QKV_N / 128, ROWS / 128), 256, 0, stream>>>(
        xb, wqkvT, b_qkv, q_ws, k_ws, nullptr, ROWS, QKV_N, EMBED, 0);

    // 3b) transpose v -> vT [B,H,D,T] (xb slot in d_out; xb dead now)
    vtrans_kernel<<<dim3(TT / 64, BB * NH), 256, 0, stream>>>(k_ws + (size_t)QSZ, vT);

    // 4) attention (local flash + memory), in-place over q_ws; XCD-swizzled flat grid
    attn_kernel<<<16 * NH * BB, 256, 0, stream>>>(
        q_ws, k_ws, vT, mem_k, mem_v);

    // 5) output projection: q_ws(bf16) @ w_out + b_out -> d_out fp32
    gemm_bt<<<dim3(EMBED / 128, ROWS / 128), 256, 0, stream>>>(
        q_ws, woutT, b_out, nullptr, nullptr, (float*)d_out, ROWS, EMBED, EMBED, 1);
}

// Round 8
// 285.914 us; speedup vs baseline: 2.3041x; 1.0913x over previous
//
#include <hip/hip_runtime.h>

#define EMBED 768
#define NH 12
#define HD 64
#define MEMN 64
#define BB 8
#define TT 1024
#define ROWS 8192
#define QKV_N 2304
#define QSZ 6291456           // B*T*C = B*NH*TT*HD (elements)

typedef short bf16x8_t __attribute__((ext_vector_type(8)));
typedef float f32x4_t __attribute__((ext_vector_type(4)));

__device__ __forceinline__ unsigned short f2b(float f){
    union { float f; unsigned int i; } v; v.f = f;
    unsigned int x = v.i;
    unsigned int r = x + 0x7fffu + ((x >> 16) & 1u);
    return (unsigned short)(r >> 16);
}

// async global->LDS, 16B per lane; lds base must be wave-uniform (lane*16 implicit)
__device__ __forceinline__ void gl16(const unsigned short* g, unsigned short* l){
    __builtin_amdgcn_global_load_lds(
        (const __attribute__((address_space(1))) void*)g,
        (__attribute__((address_space(3))) void*)l,
        16, 0, 0);
}

// ---------------- flat fp32 -> bf16 convert (8 elems/thread) ----------------
__global__ __launch_bounds__(256) void cvt_kernel(
    const float* __restrict__ in, unsigned short* __restrict__ out, int n)
{
    int i = (blockIdx.x * 256 + threadIdx.x) * 8;
    if (i >= n) return;
    float4 f0 = *(const float4*)&in[i];
    float4 f1 = *(const float4*)&in[i + 4];
    union { bf16x8_t v; unsigned short s[8]; } u;
    u.s[0] = f2b(f0.x); u.s[1] = f2b(f0.y); u.s[2] = f2b(f0.z); u.s[3] = f2b(f0.w);
    u.s[4] = f2b(f1.x); u.s[5] = f2b(f1.y); u.s[6] = f2b(f1.z); u.s[7] = f2b(f1.w);
    *(bf16x8_t*)&out[i] = u.v;
}

// ------------- fp32 [R][C] -> bf16 transposed [C][R] -------------
__global__ __launch_bounds__(256) void tcvt_kernel(
    const float* __restrict__ in, unsigned short* __restrict__ out, int R, int C)
{
    __shared__ unsigned short tile[32][33];
    int bc = blockIdx.x * 32, br = blockIdx.y * 32;
    int t = threadIdx.x;
    int lr = t >> 5, lc = t & 31;
    for (int i = 0; i < 4; i++) {
        int r = lr + i * 8;
        tile[r][lc] = f2b(in[(size_t)(br + r) * C + bc + lc]);
    }
    __syncthreads();
    for (int i = 0; i < 4; i++) {
        int r = lr + i * 8;
        out[(size_t)(bc + r) * R + br + lc] = tile[lc][r];
    }
}

// ---- bf16 [BH][T][D] -> [BH][D][T] transpose, coalesced both sides ----
// NOTE: do NOT transpose in a GEMM epilogue with 2B lane-strided stores —
// round 6 measured 44x HBM write amplification (WRITE_SIZE 38MB -> 1.67GB).
__global__ __launch_bounds__(256) void vtrans_kernel(
    const unsigned short* __restrict__ in, unsigned short* __restrict__ out)
{
    __shared__ unsigned short tile[64][72];   // row stride 144B -> b128-aligned
    int t0 = blockIdx.x * 64;
    int bh = blockIdx.y;
    const unsigned short* ip = in + ((size_t)bh * TT + t0) * 64;
    unsigned short* op = out + ((size_t)bh * 64) * TT + t0;
    int t = threadIdx.x;
    for (int i = 0; i < 2; i++) {
        int idx = i * 256 + t;
        int r = idx >> 3, c8 = (idx & 7) * 8;           // r = t-row, c8 = d
        *(bf16x8_t*)&tile[r][c8] = *(const bf16x8_t*)&ip[(size_t)r * 64 + c8];
    }
    __syncthreads();
    for (int i = 0; i < 2; i++) {
        int idx = i * 256 + t;
        int d = idx >> 3, tc8 = (idx & 7) * 8;          // d = out row, tc8 = t offset
        union { bf16x8_t v; unsigned short s[8]; } u;
        for (int j = 0; j < 8; j++) u.s[j] = tile[tc8 + j][d];
        *(bf16x8_t*)&op[(size_t)d * TT + tc8] = u.v;
    }
}

// ---- m97-style 128x128 bf16 GEMM: A (MxK bf16), BT (NxK bf16), bias fp32 ----
__global__ __launch_bounds__(256) void gemm_bt(
    const unsigned short* __restrict__ A,
    const unsigned short* __restrict__ BT,
    const float* __restrict__ bias,
    unsigned short* __restrict__ dq,
    unsigned short* __restrict__ dkv,
    float* __restrict__ df,
    int M, int N, int K, int mode)
{
    __shared__ unsigned short As[4096];   // 128 x 32, no pad (global_load_lds layout)
    __shared__ unsigned short Bs[4096];
    const int t = threadIdx.x;
    const int wave = t >> 6, lane = t & 63;
    const int ln = lane & 15, lq = lane >> 4;
    const int wm = (wave >> 1) * 64, wn = (wave & 1) * 64;
    const int bm = blockIdx.y * 128, bn = blockIdx.x * 128;

    f32x4_t acc[4][4];
    for (int i = 0; i < 4; i++)
        for (int j = 0; j < 4; j++) acc[i][j] = (f32x4_t)(0.f);

    const int srow = wave * 16 + (lane >> 2);
    const int scol = (lane & 3) * 8;
    unsigned short* a0 = &As[wave * 512];
    unsigned short* a1 = &As[2048 + wave * 512];
    unsigned short* b0 = &Bs[wave * 512];
    unsigned short* b1 = &Bs[2048 + wave * 512];
    const unsigned short* Ap = A + (size_t)(bm + srow) * K + scol;
    const unsigned short* Bp = BT + (size_t)(bn + srow) * K + scol;

    for (int k0 = 0; k0 < K; k0 += 32) {
        __syncthreads();
        gl16(Ap + k0, a0);
        gl16(Ap + (size_t)64 * K + k0, a1);
        gl16(Bp + k0, b0);
        gl16(Bp + (size_t)64 * K + k0, b1);
        __syncthreads();

        bf16x8_t af[4], bfr[4];
        for (int mt = 0; mt < 4; mt++)
            af[mt] = *(bf16x8_t*)&As[(wm + mt * 16 + ln) * 32 + lq * 8];
        for (int nt = 0; nt < 4; nt++)
            bfr[nt] = *(bf16x8_t*)&Bs[(wn + nt * 16 + ln) * 32 + lq * 8];
        for (int mt = 0; mt < 4; mt++)
            for (int nt = 0; nt < 4; nt++)
                acc[mt][nt] = __builtin_amdgcn_mfma_f32_16x16x32_bf16(
                    af[mt], bfr[nt], acc[mt][nt], 0, 0, 0);
    }

    const float QSCALE = 0.125f * 1.44269504088896340736f;  // folded softmax scale (exp2 domain)
    for (int nt = 0; nt < 4; nt++) {
        int c = bn + wn + nt * 16 + ln;
        float bv = bias[c];
        for (int mt = 0; mt < 4; mt++) {
            for (int r = 0; r < 4; r++) {
                int row = bm + wm + mt * 16 + lq * 4 + r;
                float val = acc[mt][nt][r] + bv;
                if (mode == 0) {
                    int bb = row >> 10, tt = row & 1023;
                    int s = c / 768; int rem = c - s * 768;
                    int h = rem >> 6, d = rem & 63;
                    if (s == 0) {
                        dq[(size_t)row * 768 + rem] = f2b(val * QSCALE);
                    } else {
                        dkv[(size_t)(s - 1) * QSZ +
                            (((size_t)(bb * 12 + h) * 1024 + tt) << 6) + d] = f2b(val);
                    }
                } else {
                    df[(size_t)row * N + c] = val;
                }
            }
        }
    }
}

// ---- memory projection (tiny): writes mem_k [H,M,D] and mem_v [H,D,M] ----
__global__ __launch_bounds__(256) void memproj_kernel(
    const float* __restrict__ A,
    const float* __restrict__ B,
    const float* __restrict__ bias,
    unsigned short* __restrict__ dmem_k,
    unsigned short* __restrict__ dmem_v)
{
    __shared__ unsigned short As[64][40];
    __shared__ unsigned short Bs[64][40];   // transposed: Bs[n][k]
    int t = threadIdx.x;
    int wave = t >> 6, lane = t & 63;
    int ln = lane & 15, lq = lane >> 4;
    int bn = blockIdx.x * 64;
    const int K = EMBED, N = EMBED;

    f32x4_t acc[4];
    for (int i = 0; i < 4; i++) acc[i] = (f32x4_t)(0.f);

    int sm = t >> 2, sk = (t & 3) * 8;
    int bk = t >> 3, bn8 = (t & 7) * 8;

    for (int k0 = 0; k0 < K; k0 += 32) {
        __syncthreads();
        {
            float4 f0 = *(const float4*)&A[(size_t)sm * K + k0 + sk];
            float4 f1 = *(const float4*)&A[(size_t)sm * K + k0 + sk + 4];
            unsigned short* ap = &As[sm][sk];
            ap[0] = f2b(f0.x); ap[1] = f2b(f0.y); ap[2] = f2b(f0.z); ap[3] = f2b(f0.w);
            ap[4] = f2b(f1.x); ap[5] = f2b(f1.y); ap[6] = f2b(f1.z); ap[7] = f2b(f1.w);
        }
        {
            float4 g0 = *(const float4*)&B[(size_t)(k0 + bk) * N + bn + bn8];
            float4 g1 = *(const float4*)&B[(size_t)(k0 + bk) * N + bn + bn8 + 4];
            Bs[bn8 + 0][bk] = f2b(g0.x); Bs[bn8 + 1][bk] = f2b(g0.y);
            Bs[bn8 + 2][bk] = f2b(g0.z); Bs[bn8 + 3][bk] = f2b(g0.w);
            Bs[bn8 + 4][bk] = f2b(g1.x); Bs[bn8 + 5][bk] = f2b(g1.y);
            Bs[bn8 + 6][bk] = f2b(g1.z); Bs[bn8 + 7][bk] = f2b(g1.w);
        }
        __syncthreads();
        bf16x8_t a = *(bf16x8_t*)&As[wave * 16 + ln][lq * 8];
        for (int nt = 0; nt < 4; nt++) {
            bf16x8_t bf = *(bf16x8_t*)&Bs[nt * 16 + ln][lq * 8];
            acc[nt] = __builtin_amdgcn_mfma_f32_16x16x32_bf16(a, bf, acc[nt], 0, 0, 0);
        }
    }

    for (int nt = 0; nt < 4; nt++) {
        int c = bn + nt * 16 + ln;
        float bv = bias[c];
        for (int r = 0; r < 4; r++) {
            int row = wave * 16 + lq * 4 + r;   // m index 0..63
            int h = c >> 6, d = c & 63;
            unsigned short o = f2b(acc[nt][r] + bv);
            dmem_k[((h * 64 + row) << 6) + d] = o;   // [H,M,D]
            dmem_v[((h * 64 + d) << 6) + row] = o;   // [H,D,M] (49K elems: amp harmless)
        }
    }
}

// ---- flash attention, unnormalized exp2, XOR-swizzled LDS (64-wide tiles have
// row stride 128B = 0 mod 32 banks -> chunk index is the only bank source; swizzle
// chunk ^= row&7 at staging (free: folded into per-lane global address) and read
// at lane-constant (lq^(ln&7)) -> b128 reads hit the 8-cycle structural floor. ----
__global__ __launch_bounds__(256) void attn_kernel(
    unsigned short* __restrict__ qio,           // [B,T,768] bf16, in/out (q pre-scaled)
    const unsigned short* __restrict__ k_ws,    // [B,H,T,D] bf16
    const unsigned short* __restrict__ vT_ws,   // [B,H,D,T] bf16 (transposed)
    const unsigned short* __restrict__ mem_k,   // [H,M,D]   bf16
    const unsigned short* __restrict__ mem_v)   // [H,D,M]   bf16
{
    __shared__ unsigned short Qs[4096];   // 64 x 64, XOR-swizzled chunks
    __shared__ unsigned short Ks[4096];
    __shared__ unsigned short Vs[4096];   // rows = d, cols = key (from global V^T)
    unsigned short* Ps = Qs;              // Qs dead after aq hoist

    const int t = threadIdx.x;
    const int wave = t >> 6, lane = t & 63;
    const int ln = lane & 15, lq = lane >> 4;
    const int rl = lane >> 3;                  // staging row 0..7
    const int cl = ((lane & 7) ^ rl) * 8;      // swizzled staging chunk (u16 offset)

    // XCD swizzle: all 16 q-tiles of one (b,h) land on one XCD -> K/V stays in its L2
    int bid = blockIdx.x;
    int xcd = bid & 7, rest = bid >> 3;
    int bh = xcd * 12 + (rest >> 4);   // 0..95 == b*NH + h
    int qt = rest & 15;
    int b = bh / 12, h = bh - b * 12;

    unsigned short* qp = qio + ((size_t)(b * TT + qt * 64)) * 768 + h * 64;
    const unsigned short* kp = k_ws + (size_t)bh * TT * 64;
    const unsigned short* vp = vT_ws + ((size_t)bh << 16);       // [d][t]
    const unsigned short* mkp = mem_k + h * 4096;
    const unsigned short* mvp = mem_v + h * 4096;

    // stage Q (swizzled), then hoist the wave's A-fragments
    {
        const unsigned short* qg = qp + (size_t)(wave * 8 + rl) * 768 + cl;
        gl16(qg, &Qs[wave * 512]);
        gl16(qg + (size_t)32 * 768, &Qs[2048 + wave * 512]);
    }
    __syncthreads();
    const int e0 = (lq ^ (ln & 7)) * 8;        // swizzled kk=0 chunk offset (u16)
    const int e1 = ((lq ^ (ln & 7)) ^ 4) * 8;  // swizzled kk=1 chunk offset
    bf16x8_t aq0 = *(bf16x8_t*)&Qs[(wave * 16 + ln) * 64 + e0];
    bf16x8_t aq1 = *(bf16x8_t*)&Qs[(wave * 16 + ln) * 64 + e1];

    // staging addresses (lane-resolved once)
    const unsigned short* kg = kp + (wave * 8 + rl) * 64 + cl;
    const unsigned short* vg = vp + (size_t)(wave * 8 + rl) * 1024 + cl;
    unsigned short* ksd0 = &Ks[wave * 512];
    unsigned short* ksd1 = &Ks[2048 + wave * 512];
    unsigned short* vsd0 = &Vs[wave * 512];
    unsigned short* vsd1 = &Vs[2048 + wave * 512];

    // Ps write constants (swizzle mask = row&7 = ((lq&1)<<2)^r)
    const int hi3 = ln >> 3, lo3 = ln & 7;
    const int pm = (lq & 1) << 2;
    const int pw0 = (wave * 16 + lq * 4) * 64 + lo3;

    float lsum[4] = {0.f, 0.f, 0.f, 0.f};
    f32x4_t accO[4];
    for (int nt = 0; nt < 4; nt++) accO[nt] = (f32x4_t)(0.f);

    for (int kt = 0; kt < 16; kt++) {
        __syncthreads();                       // prev Ks/Vs/Ps reads done (iter0: aq reads done)
        gl16(kg + kt * 4096, ksd0);
        gl16(kg + kt * 4096 + 2048, ksd1);
        gl16(vg + kt * 64, vsd0);
        gl16(vg + (size_t)32 * 1024 + kt * 64, vsd1);
        __syncthreads();                       // drains vmcnt -> tiles visible

        f32x4_t s[4];
        for (int nt = 0; nt < 4; nt++) s[nt] = (f32x4_t)(0.f);
        for (int nt = 0; nt < 4; nt++)
            s[nt] = __builtin_amdgcn_mfma_f32_16x16x32_bf16(
                aq0, *(bf16x8_t*)&Ks[(nt * 16 + ln) * 64 + e0], s[nt], 0, 0, 0);
        for (int nt = 0; nt < 4; nt++)
            s[nt] = __builtin_amdgcn_mfma_f32_16x16x32_bf16(
                aq1, *(bf16x8_t*)&Ks[(nt * 16 + ln) * 64 + e1], s[nt], 0, 0, 0);

        for (int nt = 0; nt < 4; nt++) {
            for (int r = 0; r < 4; r++) {
                float p = exp2f(s[nt][r]);
                lsum[r] += p;
                int chp = (nt * 2 + hi3) ^ pm ^ r;
                Ps[pw0 + r * 64 + chp * 8] = f2b(p);
            }
        }
        // Ps slab is wave-private: no barrier needed
        {
            bf16x8_t a0 = *(bf16x8_t*)&Ps[(wave * 16 + ln) * 64 + e0];
            bf16x8_t a1 = *(bf16x8_t*)&Ps[(wave * 16 + ln) * 64 + e1];
            for (int nt = 0; nt < 4; nt++) {
                accO[nt] = __builtin_amdgcn_mfma_f32_16x16x32_bf16(
                    a0, *(bf16x8_t*)&Vs[(nt * 16 + ln) * 64 + e0], accO[nt], 0, 0, 0);
                accO[nt] = __builtin_amdgcn_mfma_f32_16x16x32_bf16(
                    a1, *(bf16x8_t*)&Vs[(nt * 16 + ln) * 64 + e1], accO[nt], 0, 0, 0);
            }
        }
    }

    // memory attention: independent unnormalized softmax over 64 projected-memory keys
    __syncthreads();
    {
        const unsigned short* mk = mkp + (wave * 8 + rl) * 64 + cl;
        const unsigned short* mv = mvp + (wave * 8 + rl) * 64 + cl;
        gl16(mk, ksd0);
        gl16(mk + 2048, ksd1);
        gl16(mv, vsd0);
        gl16(mv + 2048, vsd1);
    }
    __syncthreads();

    f32x4_t s2[4];
    for (int nt = 0; nt < 4; nt++) s2[nt] = (f32x4_t)(0.f);
    for (int nt = 0; nt < 4; nt++)
        s2[nt] = __builtin_amdgcn_mfma_f32_16x16x32_bf16(
            aq0, *(bf16x8_t*)&Ks[(nt * 16 + ln) * 64 + e0], s2[nt], 0, 0, 0);
    for (int nt = 0; nt < 4; nt++)
        s2[nt] = __builtin_amdgcn_mfma_f32_16x16x32_bf16(
            aq1, *(bf16x8_t*)&Ks[(nt * 16 + ln) * 64 + e1], s2[nt], 0, 0, 0);

    float l2[4] = {0.f, 0.f, 0.f, 0.f};
    for (int nt = 0; nt < 4; nt++) {
        for (int r = 0; r < 4; r++) {
            float p = exp2f(s2[nt][r]);
            l2[r] += p;
            int chp = (nt * 2 + hi3) ^ pm ^ r;
            Ps[pw0 + r * 64 + chp * 8] = f2b(p);
        }
    }
    f32x4_t accM[4];
    for (int nt = 0; nt < 4; nt++) accM[nt] = (f32x4_t)(0.f);
    {
        bf16x8_t a0 = *(bf16x8_t*)&Ps[(wave * 16 + ln) * 64 + e0];
        bf16x8_t a1 = *(bf16x8_t*)&Ps[(wave * 16 + ln) * 64 + e1];
        for (int nt = 0; nt < 4; nt++) {
            accM[nt] = __builtin_amdgcn_mfma_f32_16x16x32_bf16(
                a0, *(bf16x8_t*)&Vs[(nt * 16 + ln) * 64 + e0], accM[nt], 0, 0, 0);
            accM[nt] = __builtin_amdgcn_mfma_f32_16x16x32_bf16(
                a1, *(bf16x8_t*)&Vs[(nt * 16 + ln) * 64 + e1], accM[nt], 0, 0, 0);
        }
    }

    // single deferred cross-lane reduction of the denominators
    float inv[4], inv2[4];
    for (int r = 0; r < 4; r++) {
        float a = lsum[r], c = l2[r];
        a += __shfl_xor(a, 1); a += __shfl_xor(a, 2);
        a += __shfl_xor(a, 4); a += __shfl_xor(a, 8);
        c += __shfl_xor(c, 1); c += __shfl_xor(c, 2);
        c += __shfl_xor(c, 4); c += __shfl_xor(c, 8);
        inv[r] = 1.f / a;
        inv2[r] = 1.f / c;
    }

    // in-place write over this block's own q slice (staged to LDS at entry)
    for (int nt = 0; nt < 4; nt++) {
        for (int r = 0; r < 4; r++) {
            int lrow = wave * 16 + lq * 4 + r;
            int lcol = nt * 16 + ln;
            float val = accO[nt][r] * inv[r] + accM[nt][r] * inv2[r];
            qp[(size_t)lrow * 768 + lcol] = f2b(val);
        }
    }
}

// ---------------- host ----------------
extern "C" void kernel_launch(void* const* d_in, const int* in_sizes, int n_in,
                              void* d_out, int out_size, void* d_ws, size_t ws_size,
                              hipStream_t stream) {
    const float* x      = (const float*)d_in[0];
    const float* w_qkv  = (const float*)d_in[1];
    const float* b_qkv  = (const float*)d_in[2];
    const float* w_out  = (const float*)d_in[3];
    const float* b_out  = (const float*)d_in[4];
    const float* w_mem  = (const float*)d_in[5];
    const float* b_mem  = (const float*)d_in[6];
    const float* memory = (const float*)d_in[7];

    unsigned short* ws = (unsigned short*)d_ws;
    unsigned short* q_ws   = ws;                         // [B,T,C] bf16; attn writes in-place
    unsigned short* k_ws   = ws + (size_t)QSZ;           // [B,H,T,D]; v ([B,H,T,D]) at +QSZ
    unsigned short* woutT  = ws + 3 * (size_t)QSZ;       // [768][768] bf16 (N x K)
    unsigned short* mem_k  = woutT + (size_t)EMBED * EMBED;  // [H,M,D] bf16
    unsigned short* mem_v  = mem_k + (size_t)NH * MEMN * HD; // [H,D,M] bf16

    // d_out multi-use: xb + wqkvT live until QKV gemm; then vT reuses xb's slot;
    // out-proj finally overwrites everything with fp32.
    unsigned short* xb    = (unsigned short*)d_out;      // [8192][768] bf16
    unsigned short* wqkvT = xb + (size_t)QSZ;            // [2304][768] bf16
    unsigned short* vT    = (unsigned short*)d_out;      // [B,H,D,T] bf16 (after QKV gemm)

    // 1) conversions
    cvt_kernel<<<QSZ / 2048, 256, 0, stream>>>(x, xb, QSZ);
    tcvt_kernel<<<dim3(QKV_N / 32, EMBED / 32), 256, 0, stream>>>(w_qkv, wqkvT, EMBED, QKV_N);
    tcvt_kernel<<<dim3(EMBED / 32, EMBED / 32), 256, 0, stream>>>(w_out, woutT, EMBED, EMBED);

    // 2) memory projection -> mem_k [H,M,D] + mem_v [H,D,M]
    memproj_kernel<<<dim3(EMBED / 64, 1), 256, 0, stream>>>(memory, w_mem, b_mem, mem_k, mem_v);

    // 3) QKV projection: q (pre-scaled) -> q_ws; k,v -> [B,H,T,D] (coalesced stores)
    gemm_bt<<<dim3(QKV_N / 128, ROWS / 128), 256, 0, stream>>>(
        xb, wqkvT, b_qkv, q_ws, k_ws, nullptr, ROWS, QKV_N, EMBED, 0);

    // 3b) transpose v -> vT [B,H,D,T] (xb slot in d_out; xb dead now)
    vtrans_kernel<<<dim3(TT / 64, BB * NH), 256, 0, stream>>>(k_ws + (size_t)QSZ, vT);

    // 4) attention (local flash + memory), in-place over q_ws; XCD-swizzled flat grid
    attn_kernel<<<16 * NH * BB, 256, 0, stream>>>(
        q_ws, k_ws, vT, mem_k, mem_v);

    // 5) output projection: q_ws(bf16) @ w_out + b_out -> d_out fp32
    gemm_bt<<<dim3(EMBED / 128, ROWS / 128), 256, 0, stream>>>(
        q_ws, woutT, b_out, nullptr, nullptr, (float*)d_out, ROWS, EMBED, EMBED, 1);
}

// Round 9
// 261.809 us; speedup vs baseline: 2.5162x; 1.0921x over previous
//
#include <hip/hip_runtime.h>

#define EMBED 768
#define NH 12
#define HD 64
#define MEMN 64
#define BB 8
#define TT 1024
#define ROWS 8192
#define QKV_N 2304
#define QSZ 6291456           // B*T*C = B*NH*TT*HD (elements)

typedef short bf16x8_t __attribute__((ext_vector_type(8)));
typedef float f32x4_t __attribute__((ext_vector_type(4)));

__device__ __forceinline__ unsigned short f2b(float f){
    union { float f; unsigned int i; } v; v.f = f;
    unsigned int x = v.i;
    unsigned int r = x + 0x7fffu + ((x >> 16) & 1u);
    return (unsigned short)(r >> 16);
}

// async global->LDS, 16B per lane; lds base must be wave-uniform (lane*16 implicit)
__device__ __forceinline__ void gl16(const unsigned short* g, unsigned short* l){
    __builtin_amdgcn_global_load_lds(
        (const __attribute__((address_space(1))) void*)g,
        (__attribute__((address_space(3))) void*)l,
        16, 0, 0);
}

// ---- fused prep: x cvt + w_qkv tcvt + w_out tcvt + memproj (one graph node) ----
// blocks [0,3072): cvt x; [3072,4800): tcvt w_qkv; [4800,5376): tcvt w_out;
// [5376,5388): memproj.
#define PREP_CVT   3072
#define PREP_TQKV  4800
#define PREP_TOUT  5376
#define PREP_TOTAL 5388

__global__ __launch_bounds__(256) void prep_kernel(
    const float* __restrict__ x,
    const float* __restrict__ w_qkv,
    const float* __restrict__ w_out,
    const float* __restrict__ memory,
    const float* __restrict__ w_mem,
    const float* __restrict__ b_mem,
    unsigned short* __restrict__ xb,
    unsigned short* __restrict__ wqkvT,
    unsigned short* __restrict__ woutT,
    unsigned short* __restrict__ mem_k,
    unsigned short* __restrict__ mem_v)
{
    __shared__ unsigned short pool[5120];   // memproj: 2x 64x40; tcvt: 32x33
    const int bid = blockIdx.x;
    const int t = threadIdx.x;

    if (bid < PREP_CVT) {
        int i = bid * 2048 + t * 8;
        float4 f0 = *(const float4*)&x[i];
        float4 f1 = *(const float4*)&x[i + 4];
        union { bf16x8_t v; unsigned short s[8]; } u;
        u.s[0] = f2b(f0.x); u.s[1] = f2b(f0.y); u.s[2] = f2b(f0.z); u.s[3] = f2b(f0.w);
        u.s[4] = f2b(f1.x); u.s[5] = f2b(f1.y); u.s[6] = f2b(f1.z); u.s[7] = f2b(f1.w);
        *(bf16x8_t*)&xb[i] = u.v;
    } else if (bid < PREP_TOUT) {
        // transpose-convert: in fp32 [R][C] -> out bf16 [C][R]
        const float* in; unsigned short* out; int R, C, loc;
        if (bid < PREP_TQKV) { in = w_qkv; out = wqkvT; R = EMBED; C = QKV_N; loc = bid - PREP_CVT; }
        else                 { in = w_out; out = woutT; R = EMBED; C = EMBED; loc = bid - PREP_TQKV; }
        int nbc = C / 32;
        int bc = (loc % nbc) * 32, br = (loc / nbc) * 32;
        unsigned short (*tile)[33] = (unsigned short(*)[33])pool;
        int lr = t >> 5, lc = t & 31;
        for (int i = 0; i < 4; i++) {
            int r = lr + i * 8;
            tile[r][lc] = f2b(in[(size_t)(br + r) * C + bc + lc]);
        }
        __syncthreads();
        for (int i = 0; i < 4; i++) {
            int r = lr + i * 8;
            out[(size_t)(bc + r) * R + br + lc] = tile[lc][r];
        }
    } else {
        // memproj: (64x768) @ w_mem + b_mem -> mem_k [H,M,D], mem_v [H,D,M]
        unsigned short (*As)[40] = (unsigned short(*)[40])pool;
        unsigned short (*Bs)[40] = (unsigned short(*)[40])(pool + 2560);
        int wave = t >> 6, lane = t & 63;
        int ln = lane & 15, lq = lane >> 4;
        int bn = (bid - PREP_TOUT) * 64;
        const int K = EMBED, N = EMBED;

        f32x4_t acc[4];
        for (int i = 0; i < 4; i++) acc[i] = (f32x4_t)(0.f);
        int sm = t >> 2, sk = (t & 3) * 8;
        int bk = t >> 3, bn8 = (t & 7) * 8;

        for (int k0 = 0; k0 < K; k0 += 32) {
            __syncthreads();
            {
                float4 f0 = *(const float4*)&memory[(size_t)sm * K + k0 + sk];
                float4 f1 = *(const float4*)&memory[(size_t)sm * K + k0 + sk + 4];
                unsigned short* ap = &As[sm][sk];
                ap[0] = f2b(f0.x); ap[1] = f2b(f0.y); ap[2] = f2b(f0.z); ap[3] = f2b(f0.w);
                ap[4] = f2b(f1.x); ap[5] = f2b(f1.y); ap[6] = f2b(f1.z); ap[7] = f2b(f1.w);
            }
            {
                float4 g0 = *(const float4*)&w_mem[(size_t)(k0 + bk) * N + bn + bn8];
                float4 g1 = *(const float4*)&w_mem[(size_t)(k0 + bk) * N + bn + bn8 + 4];
                Bs[bn8 + 0][bk] = f2b(g0.x); Bs[bn8 + 1][bk] = f2b(g0.y);
                Bs[bn8 + 2][bk] = f2b(g0.z); Bs[bn8 + 3][bk] = f2b(g0.w);
                Bs[bn8 + 4][bk] = f2b(g1.x); Bs[bn8 + 5][bk] = f2b(g1.y);
                Bs[bn8 + 6][bk] = f2b(g1.z); Bs[bn8 + 7][bk] = f2b(g1.w);
            }
            __syncthreads();
            bf16x8_t a = *(bf16x8_t*)&As[wave * 16 + ln][lq * 8];
            for (int nt = 0; nt < 4; nt++) {
                bf16x8_t bf = *(bf16x8_t*)&Bs[nt * 16 + ln][lq * 8];
                acc[nt] = __builtin_amdgcn_mfma_f32_16x16x32_bf16(a, bf, acc[nt], 0, 0, 0);
            }
        }
        for (int nt = 0; nt < 4; nt++) {
            int c = bn + nt * 16 + ln;
            float bv = b_mem[c];
            for (int r = 0; r < 4; r++) {
                int row = wave * 16 + lq * 4 + r;
                int h = c >> 6, d = c & 63;
                unsigned short o = f2b(acc[nt][r] + bv);
                mem_k[((h * 64 + row) << 6) + d] = o;   // [H,M,D]
                mem_v[((h * 64 + d) << 6) + row] = o;   // [H,D,M]
            }
        }
    }
}

// ---- bf16 [BH][T][D] -> [BH][D][T] transpose, coalesced both sides ----
// NOTE: never transpose in a GEMM epilogue with 2B lane-strided stores —
// round 6 measured 44x HBM write amplification.
__global__ __launch_bounds__(256) void vtrans_kernel(
    const unsigned short* __restrict__ in, unsigned short* __restrict__ out)
{
    __shared__ unsigned short tile[64][72];
    int t0 = blockIdx.x * 64;
    int bh = blockIdx.y;
    const unsigned short* ip = in + ((size_t)bh * TT + t0) * 64;
    unsigned short* op = out + ((size_t)bh * 64) * TT + t0;
    int t = threadIdx.x;
    for (int i = 0; i < 2; i++) {
        int idx = i * 256 + t;
        int r = idx >> 3, c8 = (idx & 7) * 8;
        *(bf16x8_t*)&tile[r][c8] = *(const bf16x8_t*)&ip[(size_t)r * 64 + c8];
    }
    __syncthreads();
    for (int i = 0; i < 2; i++) {
        int idx = i * 256 + t;
        int d = idx >> 3, tc8 = (idx & 7) * 8;
        union { bf16x8_t v; unsigned short s[8]; } u;
        for (int j = 0; j < 8; j++) u.s[j] = tile[tc8 + j][d];
        *(bf16x8_t*)&op[(size_t)d * TT + tc8] = u.v;
    }
}

// ---- 128x128 bf16 GEMM, BK=64 (half the barrier drains of BK=32), XOR-swizzled
// LDS (64-wide rows: stride 32dw == 0 mod 32 banks, chunk^=row&7 restores the
// 8-cycle b128 floor). A (MxK), BT (NxK), bias fp32. ----
__global__ __launch_bounds__(256) void gemm_bt(
    const unsigned short* __restrict__ A,
    const unsigned short* __restrict__ BT,
    const float* __restrict__ bias,
    unsigned short* __restrict__ dq,
    unsigned short* __restrict__ dkv,
    float* __restrict__ df,
    int M, int N, int K, int mode)
{
    __shared__ unsigned short As[8192];   // 128 x 64
    __shared__ unsigned short Bs[8192];
    const int t = threadIdx.x;
    const int wave = t >> 6, lane = t & 63;
    const int ln = lane & 15, lq = lane >> 4;
    const int wm = (wave >> 1) * 64, wn = (wave & 1) * 64;
    const int bm = blockIdx.y * 128, bn = blockIdx.x * 128;

    f32x4_t acc[4][4];
    for (int i = 0; i < 4; i++)
        for (int j = 0; j < 4; j++) acc[i][j] = (f32x4_t)(0.f);

    // staging: wave w call i covers rows w*32+i*8 .. +8; lane l -> row +(l>>3),
    // swizzled chunk (l&7)^(l>>3) (row&7 == l>>3 since w*32,i*8 are mult of 8)
    const int rl8 = lane >> 3;
    const int swz = ((lane & 7) ^ rl8) * 8;
    const unsigned short* Ap = A + (size_t)(bm + wave * 32 + rl8) * K + swz;
    const unsigned short* Bp = BT + (size_t)(bn + wave * 32 + rl8) * K + swz;
    unsigned short* asd = &As[wave * 2048];
    unsigned short* bsd = &Bs[wave * 2048];

    // fragment chunk offsets: row&7 == ln&7
    const int e0 = (lq ^ (ln & 7)) * 8;
    const int e1 = e0 ^ 32;

    for (int k0 = 0; k0 < K; k0 += 64) {
        __syncthreads();
        for (int i = 0; i < 4; i++) {
            gl16(Ap + (size_t)(i * 8) * K + k0, asd + i * 512);
            gl16(Bp + (size_t)(i * 8) * K + k0, bsd + i * 512);
        }
        __syncthreads();

        {
            bf16x8_t af[4], bfr[4];
            for (int mt = 0; mt < 4; mt++)
                af[mt] = *(bf16x8_t*)&As[(wm + mt * 16 + ln) * 64 + e0];
            for (int nt = 0; nt < 4; nt++)
                bfr[nt] = *(bf16x8_t*)&Bs[(wn + nt * 16 + ln) * 64 + e0];
            for (int mt = 0; mt < 4; mt++)
                for (int nt = 0; nt < 4; nt++)
                    acc[mt][nt] = __builtin_amdgcn_mfma_f32_16x16x32_bf16(
                        af[mt], bfr[nt], acc[mt][nt], 0, 0, 0);
        }
        {
            bf16x8_t af[4], bfr[4];
            for (int mt = 0; mt < 4; mt++)
                af[mt] = *(bf16x8_t*)&As[(wm + mt * 16 + ln) * 64 + e1];
            for (int nt = 0; nt < 4; nt++)
                bfr[nt] = *(bf16x8_t*)&Bs[(wn + nt * 16 + ln) * 64 + e1];
            for (int mt = 0; mt < 4; mt++)
                for (int nt = 0; nt < 4; nt++)
                    acc[mt][nt] = __builtin_amdgcn_mfma_f32_16x16x32_bf16(
                        af[mt], bfr[nt], acc[mt][nt], 0, 0, 0);
        }
    }

    const float QSCALE = 0.125f * 1.44269504088896340736f;  // folded softmax scale
    if (mode == 0) {
        const int s = bn / 768;          // block-uniform: 768 % 128 == 0
        for (int nt = 0; nt < 4; nt++) {
            int c = bn + wn + nt * 16 + ln;
            int rem = c - s * 768;
            int h = rem >> 6, d = rem & 63;
            float bv = bias[c];
            for (int mt = 0; mt < 4; mt++) {
                for (int r = 0; r < 4; r++) {
                    int row = bm + wm + mt * 16 + lq * 4 + r;
                    float val = acc[mt][nt][r] + bv;
                    if (s == 0) {
                        dq[(size_t)row * 768 + rem] = f2b(val * QSCALE);
                    } else {
                        int bb = row >> 10, tt = row & 1023;
                        dkv[(size_t)(s - 1) * QSZ +
                            (((size_t)(bb * 12 + h) * 1024 + tt) << 6) + d] = f2b(val);
                    }
                }
            }
        }
    } else {
        for (int nt = 0; nt < 4; nt++) {
            int c = bn + wn + nt * 16 + ln;
            float bv = bias[c];
            for (int mt = 0; mt < 4; mt++)
                for (int r = 0; r < 4; r++) {
                    int row = bm + wm + mt * 16 + lq * 4 + r;
                    df[(size_t)row * N + c] = acc[mt][nt][r] + bv;
                }
        }
    }
}

// ---- flash attention, unnormalized exp2, XOR-swizzled LDS (unchanged from r8) ----
__global__ __launch_bounds__(256) void attn_kernel(
    unsigned short* __restrict__ qio,           // [B,T,768] bf16, in/out (q pre-scaled)
    const unsigned short* __restrict__ k_ws,    // [B,H,T,D] bf16
    const unsigned short* __restrict__ vT_ws,   // [B,H,D,T] bf16 (transposed)
    const unsigned short* __restrict__ mem_k,   // [H,M,D]   bf16
    const unsigned short* __restrict__ mem_v)   // [H,D,M]   bf16
{
    __shared__ unsigned short Qs[4096];
    __shared__ unsigned short Ks[4096];
    __shared__ unsigned short Vs[4096];
    unsigned short* Ps = Qs;              // Qs dead after aq hoist

    const int t = threadIdx.x;
    const int wave = t >> 6, lane = t & 63;
    const int ln = lane & 15, lq = lane >> 4;
    const int rl = lane >> 3;
    const int cl = ((lane & 7) ^ rl) * 8;

    int bid = blockIdx.x;
    int xcd = bid & 7, rest = bid >> 3;
    int bh = xcd * 12 + (rest >> 4);
    int qt = rest & 15;
    int b = bh / 12, h = bh - b * 12;

    unsigned short* qp = qio + ((size_t)(b * TT + qt * 64)) * 768 + h * 64;
    const unsigned short* kp = k_ws + (size_t)bh * TT * 64;
    const unsigned short* vp = vT_ws + ((size_t)bh << 16);
    const unsigned short* mkp = mem_k + h * 4096;
    const unsigned short* mvp = mem_v + h * 4096;

    {
        const unsigned short* qg = qp + (size_t)(wave * 8 + rl) * 768 + cl;
        gl16(qg, &Qs[wave * 512]);
        gl16(qg + (size_t)32 * 768, &Qs[2048 + wave * 512]);
    }
    __syncthreads();
    const int e0 = (lq ^ (ln & 7)) * 8;
    const int e1 = ((lq ^ (ln & 7)) ^ 4) * 8;
    bf16x8_t aq0 = *(bf16x8_t*)&Qs[(wave * 16 + ln) * 64 + e0];
    bf16x8_t aq1 = *(bf16x8_t*)&Qs[(wave * 16 + ln) * 64 + e1];

    const unsigned short* kg = kp + (wave * 8 + rl) * 64 + cl;
    const unsigned short* vg = vp + (size_t)(wave * 8 + rl) * 1024 + cl;
    unsigned short* ksd0 = &Ks[wave * 512];
    unsigned short* ksd1 = &Ks[2048 + wave * 512];
    unsigned short* vsd0 = &Vs[wave * 512];
    unsigned short* vsd1 = &Vs[2048 + wave * 512];

    const int hi3 = ln >> 3, lo3 = ln & 7;
    const int pm = (lq & 1) << 2;
    const int pw0 = (wave * 16 + lq * 4) * 64 + lo3;

    float lsum[4] = {0.f, 0.f, 0.f, 0.f};
    f32x4_t accO[4];
    for (int nt = 0; nt < 4; nt++) accO[nt] = (f32x4_t)(0.f);

    for (int kt = 0; kt < 16; kt++) {
        __syncthreads();
        gl16(kg + kt * 4096, ksd0);
        gl16(kg + kt * 4096 + 2048, ksd1);
        gl16(vg + kt * 64, vsd0);
        gl16(vg + (size_t)32 * 1024 + kt * 64, vsd1);
        __syncthreads();

        f32x4_t s[4];
        for (int nt = 0; nt < 4; nt++) s[nt] = (f32x4_t)(0.f);
        for (int nt = 0; nt < 4; nt++)
            s[nt] = __builtin_amdgcn_mfma_f32_16x16x32_bf16(
                aq0, *(bf16x8_t*)&Ks[(nt * 16 + ln) * 64 + e0], s[nt], 0, 0, 0);
        for (int nt = 0; nt < 4; nt++)
            s[nt] = __builtin_amdgcn_mfma_f32_16x16x32_bf16(
                aq1, *(bf16x8_t*)&Ks[(nt * 16 + ln) * 64 + e1], s[nt], 0, 0, 0);

        for (int nt = 0; nt < 4; nt++) {
            for (int r = 0; r < 4; r++) {
                float p = exp2f(s[nt][r]);
                lsum[r] += p;
                int chp = (nt * 2 + hi3) ^ pm ^ r;
                Ps[pw0 + r * 64 + chp * 8] = f2b(p);
            }
        }
        {
            bf16x8_t a0 = *(bf16x8_t*)&Ps[(wave * 16 + ln) * 64 + e0];
            bf16x8_t a1 = *(bf16x8_t*)&Ps[(wave * 16 + ln) * 64 + e1];
            for (int nt = 0; nt < 4; nt++) {
                accO[nt] = __builtin_amdgcn_mfma_f32_16x16x32_bf16(
                    a0, *(bf16x8_t*)&Vs[(nt * 16 + ln) * 64 + e0], accO[nt], 0, 0, 0);
                accO[nt] = __builtin_amdgcn_mfma_f32_16x16x32_bf16(
                    a1, *(bf16x8_t*)&Vs[(nt * 16 + ln) * 64 + e1], accO[nt], 0, 0, 0);
            }
        }
    }

    __syncthreads();
    {
        const unsigned short* mk = mkp + (wave * 8 + rl) * 64 + cl;
        const unsigned short* mv = mvp + (wave * 8 + rl) * 64 + cl;
        gl16(mk, ksd0);
        gl16(mk + 2048, ksd1);
        gl16(mv, vsd0);
        gl16(mv + 2048, vsd1);
    }
    __syncthreads();

    f32x4_t s2[4];
    for (int nt = 0; nt < 4; nt++) s2[nt] = (f32x4_t)(0.f);
    for (int nt = 0; nt < 4; nt++)
        s2[nt] = __builtin_amdgcn_mfma_f32_16x16x32_bf16(
            aq0, *(bf16x8_t*)&Ks[(nt * 16 + ln) * 64 + e0], s2[nt], 0, 0, 0);
    for (int nt = 0; nt < 4; nt++)
        s2[nt] = __builtin_amdgcn_mfma_f32_16x16x32_bf16(
            aq1, *(bf16x8_t*)&Ks[(nt * 16 + ln) * 64 + e1], s2[nt], 0, 0, 0);

    float l2[4] = {0.f, 0.f, 0.f, 0.f};
    for (int nt = 0; nt < 4; nt++) {
        for (int r = 0; r < 4; r++) {
            float p = exp2f(s2[nt][r]);
            l2[r] += p;
            int chp = (nt * 2 + hi3) ^ pm ^ r;
            Ps[pw0 + r * 64 + chp * 8] = f2b(p);
        }
    }
    f32x4_t accM[4];
    for (int nt = 0; nt < 4; nt++) accM[nt] = (f32x4_t)(0.f);
    {
        bf16x8_t a0 = *(bf16x8_t*)&Ps[(wave * 16 + ln) * 64 + e0];
        bf16x8_t a1 = *(bf16x8_t*)&Ps[(wave * 16 + ln) * 64 + e1];
        for (int nt = 0; nt < 4; nt++) {
            accM[nt] = __builtin_amdgcn_mfma_f32_16x16x32_bf16(
                a0, *(bf16x8_t*)&Vs[(nt * 16 + ln) * 64 + e0], accM[nt], 0, 0, 0);
            accM[nt] = __builtin_amdgcn_mfma_f32_16x16x32_bf16(
                a1, *(bf16x8_t*)&Vs[(nt * 16 + ln) * 64 + e1], accM[nt], 0, 0, 0);
        }
    }

    float inv[4], inv2[4];
    for (int r = 0; r < 4; r++) {
        float a = lsum[r], c = l2[r];
        a += __shfl_xor(a, 1); a += __shfl_xor(a, 2);
        a += __shfl_xor(a, 4); a += __shfl_xor(a, 8);
        c += __shfl_xor(c, 1); c += __shfl_xor(c, 2);
        c += __shfl_xor(c, 4); c += __shfl_xor(c, 8);
        inv[r] = 1.f / a;
        inv2[r] = 1.f / c;
    }

    for (int nt = 0; nt < 4; nt++) {
        for (int r = 0; r < 4; r++) {
            int lrow = wave * 16 + lq * 4 + r;
            int lcol = nt * 16 + ln;
            float val = accO[nt][r] * inv[r] + accM[nt][r] * inv2[r];
            qp[(size_t)lrow * 768 + lcol] = f2b(val);
        }
    }
}

// ---------------- host ----------------
extern "C" void kernel_launch(void* const* d_in, const int* in_sizes, int n_in,
                              void* d_out, int out_size, void* d_ws, size_t ws_size,
                              hipStream_t stream) {
    const float* x      = (const float*)d_in[0];
    const float* w_qkv  = (const float*)d_in[1];
    const float* b_qkv  = (const float*)d_in[2];
    const float* w_out  = (const float*)d_in[3];
    const float* b_out  = (const float*)d_in[4];
    const float* w_mem  = (const float*)d_in[5];
    const float* b_mem  = (const float*)d_in[6];
    const float* memory = (const float*)d_in[7];

    unsigned short* ws = (unsigned short*)d_ws;
    unsigned short* q_ws   = ws;                         // [B,T,C] bf16; attn in-place
    unsigned short* k_ws   = ws + (size_t)QSZ;           // [B,H,T,D]; v at +QSZ
    unsigned short* woutT  = ws + 3 * (size_t)QSZ;       // [768][768] bf16 (N x K)
    unsigned short* mem_k  = woutT + (size_t)EMBED * EMBED;
    unsigned short* mem_v  = mem_k + (size_t)NH * MEMN * HD;

    // d_out multi-use: xb + wqkvT live until QKV gemm; vT reuses xb's slot;
    // out-proj finally overwrites everything with fp32.
    unsigned short* xb    = (unsigned short*)d_out;      // [8192][768] bf16
    unsigned short* wqkvT = xb + (size_t)QSZ;            // [2304][768] bf16
    unsigned short* vT    = (unsigned short*)d_out;      // [B,H,D,T] bf16

    // 1) fused prep (cvt + 2 tcvt + memproj)
    prep_kernel<<<PREP_TOTAL, 256, 0, stream>>>(
        x, w_qkv, w_out, memory, w_mem, b_mem, xb, wqkvT, woutT, mem_k, mem_v);

    // 2) QKV projection: q (pre-scaled) -> q_ws; k,v -> [B,H,T,D]
    gemm_bt<<<dim3(QKV_N / 128, ROWS / 128), 256, 0, stream>>>(
        xb, wqkvT, b_qkv, q_ws, k_ws, nullptr, ROWS, QKV_N, EMBED, 0);

    // 3) transpose v -> vT [B,H,D,T]
    vtrans_kernel<<<dim3(TT / 64, BB * NH), 256, 0, stream>>>(k_ws + (size_t)QSZ, vT);

    // 4) attention (local flash + memory), in-place over q_ws
    attn_kernel<<<16 * NH * BB, 256, 0, stream>>>(q_ws, k_ws, vT, mem_k, mem_v);

    // 5) output projection: q_ws(bf16) @ w_out + b_out -> d_out fp32
    gemm_bt<<<dim3(EMBED / 128, ROWS / 128), 256, 0, stream>>>(
        q_ws, woutT, b_out, nullptr, nullptr, (float*)d_out, ROWS, EMBED, EMBED, 1);
}

// Round 10
// 254.488 us; speedup vs baseline: 2.5886x; 1.0288x over previous
//
#include <hip/hip_runtime.h>

#define EMBED 768
#define NH 12
#define HD 64
#define MEMN 64
#define BB 8
#define TT 1024
#define ROWS 8192
#define QKV_N 2304
#define QSZ 6291456           // B*T*C = B*NH*TT*HD (elements)

typedef short bf16x8_t __attribute__((ext_vector_type(8)));
typedef float f32x4_t __attribute__((ext_vector_type(4)));

__device__ __forceinline__ unsigned short f2b(float f){
    union { float f; unsigned int i; } v; v.f = f;
    unsigned int x = v.i;
    unsigned int r = x + 0x7fffu + ((x >> 16) & 1u);
    return (unsigned short)(r >> 16);
}
// round-half-up convert for non-negative values (softmax p): 1 add + fold-able shift
__device__ __forceinline__ unsigned short f2b_ru(float f){
    union { float f; unsigned int i; } v; v.f = f;
    return (unsigned short)((v.i + 0x8000u) >> 16);
}

// async global->LDS, 16B per lane; lds base must be wave-uniform (lane*16 implicit)
__device__ __forceinline__ void gl16(const unsigned short* g, unsigned short* l){
    __builtin_amdgcn_global_load_lds(
        (const __attribute__((address_space(1))) void*)g,
        (__attribute__((address_space(3))) void*)l,
        16, 0, 0);
}

// ---- fused prep: x cvt + w_qkv tcvt + w_out tcvt + memproj (one graph node) ----
#define PREP_CVT   3072
#define PREP_TQKV  4800
#define PREP_TOUT  5376
#define PREP_TOTAL 5388

__global__ __launch_bounds__(256) void prep_kernel(
    const float* __restrict__ x,
    const float* __restrict__ w_qkv,
    const float* __restrict__ w_out,
    const float* __restrict__ memory,
    const float* __restrict__ w_mem,
    const float* __restrict__ b_mem,
    unsigned short* __restrict__ xb,
    unsigned short* __restrict__ wqkvT,
    unsigned short* __restrict__ woutT,
    unsigned short* __restrict__ mem_k,
    unsigned short* __restrict__ mem_v)
{
    __shared__ unsigned short pool[5120];
    const int bid = blockIdx.x;
    const int t = threadIdx.x;

    if (bid < PREP_CVT) {
        int i = bid * 2048 + t * 8;
        float4 f0 = *(const float4*)&x[i];
        float4 f1 = *(const float4*)&x[i + 4];
        union { bf16x8_t v; unsigned short s[8]; } u;
        u.s[0] = f2b(f0.x); u.s[1] = f2b(f0.y); u.s[2] = f2b(f0.z); u.s[3] = f2b(f0.w);
        u.s[4] = f2b(f1.x); u.s[5] = f2b(f1.y); u.s[6] = f2b(f1.z); u.s[7] = f2b(f1.w);
        *(bf16x8_t*)&xb[i] = u.v;
    } else if (bid < PREP_TOUT) {
        const float* in; unsigned short* out; int R, C, loc;
        if (bid < PREP_TQKV) { in = w_qkv; out = wqkvT; R = EMBED; C = QKV_N; loc = bid - PREP_CVT; }
        else                 { in = w_out; out = woutT; R = EMBED; C = EMBED; loc = bid - PREP_TQKV; }
        int nbc = C / 32;
        int bc = (loc % nbc) * 32, br = (loc / nbc) * 32;
        unsigned short (*tile)[33] = (unsigned short(*)[33])pool;
        int lr = t >> 5, lc = t & 31;
        for (int i = 0; i < 4; i++) {
            int r = lr + i * 8;
            tile[r][lc] = f2b(in[(size_t)(br + r) * C + bc + lc]);
        }
        __syncthreads();
        for (int i = 0; i < 4; i++) {
            int r = lr + i * 8;
            out[(size_t)(bc + r) * R + br + lc] = tile[lc][r];
        }
    } else {
        unsigned short (*As)[40] = (unsigned short(*)[40])pool;
        unsigned short (*Bs)[40] = (unsigned short(*)[40])(pool + 2560);
        int wave = t >> 6, lane = t & 63;
        int ln = lane & 15, lq = lane >> 4;
        int bn = (bid - PREP_TOUT) * 64;
        const int K = EMBED, N = EMBED;

        f32x4_t acc[4];
        for (int i = 0; i < 4; i++) acc[i] = (f32x4_t)(0.f);
        int sm = t >> 2, sk = (t & 3) * 8;
        int bk = t >> 3, bn8 = (t & 7) * 8;

        for (int k0 = 0; k0 < K; k0 += 32) {
            __syncthreads();
            {
                float4 f0 = *(const float4*)&memory[(size_t)sm * K + k0 + sk];
                float4 f1 = *(const float4*)&memory[(size_t)sm * K + k0 + sk + 4];
                unsigned short* ap = &As[sm][sk];
                ap[0] = f2b(f0.x); ap[1] = f2b(f0.y); ap[2] = f2b(f0.z); ap[3] = f2b(f0.w);
                ap[4] = f2b(f1.x); ap[5] = f2b(f1.y); ap[6] = f2b(f1.z); ap[7] = f2b(f1.w);
            }
            {
                float4 g0 = *(const float4*)&w_mem[(size_t)(k0 + bk) * N + bn + bn8];
                float4 g1 = *(const float4*)&w_mem[(size_t)(k0 + bk) * N + bn + bn8 + 4];
                Bs[bn8 + 0][bk] = f2b(g0.x); Bs[bn8 + 1][bk] = f2b(g0.y);
                Bs[bn8 + 2][bk] = f2b(g0.z); Bs[bn8 + 3][bk] = f2b(g0.w);
                Bs[bn8 + 4][bk] = f2b(g1.x); Bs[bn8 + 5][bk] = f2b(g1.y);
                Bs[bn8 + 6][bk] = f2b(g1.z); Bs[bn8 + 7][bk] = f2b(g1.w);
            }
            __syncthreads();
            bf16x8_t a = *(bf16x8_t*)&As[wave * 16 + ln][lq * 8];
            for (int nt = 0; nt < 4; nt++) {
                bf16x8_t bf = *(bf16x8_t*)&Bs[nt * 16 + ln][lq * 8];
                acc[nt] = __builtin_amdgcn_mfma_f32_16x16x32_bf16(a, bf, acc[nt], 0, 0, 0);
            }
        }
        for (int nt = 0; nt < 4; nt++) {
            int c = bn + nt * 16 + ln;
            float bv = b_mem[c];
            for (int r = 0; r < 4; r++) {
                int row = wave * 16 + lq * 4 + r;
                int h = c >> 6, d = c & 63;
                unsigned short o = f2b(acc[nt][r] + bv);
                mem_k[((h * 64 + row) << 6) + d] = o;   // [H,M,D]
                mem_v[((h * 64 + d) << 6) + row] = o;   // [H,D,M]
            }
        }
    }
}

// ---- bf16 [BH][T][D] -> [BH][D][T] transpose, coalesced both sides ----
__global__ __launch_bounds__(256) void vtrans_kernel(
    const unsigned short* __restrict__ in, unsigned short* __restrict__ out)
{
    __shared__ unsigned short tile[64][72];
    int t0 = blockIdx.x * 64;
    int bh = blockIdx.y;
    const unsigned short* ip = in + ((size_t)bh * TT + t0) * 64;
    unsigned short* op = out + ((size_t)bh * 64) * TT + t0;
    int t = threadIdx.x;
    for (int i = 0; i < 2; i++) {
        int idx = i * 256 + t;
        int r = idx >> 3, c8 = (idx & 7) * 8;
        *(bf16x8_t*)&tile[r][c8] = *(const bf16x8_t*)&ip[(size_t)r * 64 + c8];
    }
    __syncthreads();
    for (int i = 0; i < 2; i++) {
        int idx = i * 256 + t;
        int d = idx >> 3, tc8 = (idx & 7) * 8;
        union { bf16x8_t v; unsigned short s[8]; } u;
        for (int j = 0; j < 8; j++) u.s[j] = tile[tc8 + j][d];
        *(bf16x8_t*)&op[(size_t)d * TT + tc8] = u.v;
    }
}

// ---- 128x128 bf16 GEMM, BK=64, XOR-swizzled LDS (unchanged from r9) ----
__global__ __launch_bounds__(256) void gemm_bt(
    const unsigned short* __restrict__ A,
    const unsigned short* __restrict__ BT,
    const float* __restrict__ bias,
    unsigned short* __restrict__ dq,
    unsigned short* __restrict__ dkv,
    float* __restrict__ df,
    int M, int N, int K, int mode)
{
    __shared__ unsigned short As[8192];   // 128 x 64
    __shared__ unsigned short Bs[8192];
    const int t = threadIdx.x;
    const int wave = t >> 6, lane = t & 63;
    const int ln = lane & 15, lq = lane >> 4;
    const int wm = (wave >> 1) * 64, wn = (wave & 1) * 64;
    const int bm = blockIdx.y * 128, bn = blockIdx.x * 128;

    f32x4_t acc[4][4];
    for (int i = 0; i < 4; i++)
        for (int j = 0; j < 4; j++) acc[i][j] = (f32x4_t)(0.f);

    const int rl8 = lane >> 3;
    const int swz = ((lane & 7) ^ rl8) * 8;
    const unsigned short* Ap = A + (size_t)(bm + wave * 32 + rl8) * K + swz;
    const unsigned short* Bp = BT + (size_t)(bn + wave * 32 + rl8) * K + swz;
    unsigned short* asd = &As[wave * 2048];
    unsigned short* bsd = &Bs[wave * 2048];

    const int e0 = (lq ^ (ln & 7)) * 8;
    const int e1 = e0 ^ 32;

    for (int k0 = 0; k0 < K; k0 += 64) {
        __syncthreads();
        for (int i = 0; i < 4; i++) {
            gl16(Ap + (size_t)(i * 8) * K + k0, asd + i * 512);
            gl16(Bp + (size_t)(i * 8) * K + k0, bsd + i * 512);
        }
        __syncthreads();

        {
            bf16x8_t af[4], bfr[4];
            for (int mt = 0; mt < 4; mt++)
                af[mt] = *(bf16x8_t*)&As[(wm + mt * 16 + ln) * 64 + e0];
            for (int nt = 0; nt < 4; nt++)
                bfr[nt] = *(bf16x8_t*)&Bs[(wn + nt * 16 + ln) * 64 + e0];
            for (int mt = 0; mt < 4; mt++)
                for (int nt = 0; nt < 4; nt++)
                    acc[mt][nt] = __builtin_amdgcn_mfma_f32_16x16x32_bf16(
                        af[mt], bfr[nt], acc[mt][nt], 0, 0, 0);
        }
        {
            bf16x8_t af[4], bfr[4];
            for (int mt = 0; mt < 4; mt++)
                af[mt] = *(bf16x8_t*)&As[(wm + mt * 16 + ln) * 64 + e1];
            for (int nt = 0; nt < 4; nt++)
                bfr[nt] = *(bf16x8_t*)&Bs[(wn + nt * 16 + ln) * 64 + e1];
            for (int mt = 0; mt < 4; mt++)
                for (int nt = 0; nt < 4; nt++)
                    acc[mt][nt] = __builtin_amdgcn_mfma_f32_16x16x32_bf16(
                        af[mt], bfr[nt], acc[mt][nt], 0, 0, 0);
        }
    }

    const float QSCALE = 0.125f * 1.44269504088896340736f;
    if (mode == 0) {
        const int s = bn / 768;
        for (int nt = 0; nt < 4; nt++) {
            int c = bn + wn + nt * 16 + ln;
            int rem = c - s * 768;
            int h = rem >> 6, d = rem & 63;
            float bv = bias[c];
            for (int mt = 0; mt < 4; mt++) {
                for (int r = 0; r < 4; r++) {
                    int row = bm + wm + mt * 16 + lq * 4 + r;
                    float val = acc[mt][nt][r] + bv;
                    if (s == 0) {
                        dq[(size_t)row * 768 + rem] = f2b(val * QSCALE);
                    } else {
                        int bb = row >> 10, tt = row & 1023;
                        dkv[(size_t)(s - 1) * QSZ +
                            (((size_t)(bb * 12 + h) * 1024 + tt) << 6) + d] = f2b(val);
                    }
                }
            }
        }
    } else {
        for (int nt = 0; nt < 4; nt++) {
            int c = bn + wn + nt * 16 + ln;
            float bv = bias[c];
            for (int mt = 0; mt < 4; mt++)
                for (int r = 0; r < 4; r++) {
                    int row = bm + wm + mt * 16 + lq * 4 + r;
                    df[(size_t)row * N + c] = acc[mt][nt][r] + bv;
                }
        }
    }
}

// ---- flash attention: 128-key kt steps (8 barrier pairs instead of 16),
// unnormalized exp2 via raw v_exp_f32, XOR-swizzled LDS, cheap f2b for P. ----
__global__ __launch_bounds__(256) void attn_kernel(
    unsigned short* __restrict__ qio,           // [B,T,768] bf16, in/out (q pre-scaled)
    const unsigned short* __restrict__ k_ws,    // [B,H,T,D] bf16
    const unsigned short* __restrict__ vT_ws,   // [B,H,D,T] bf16 (transposed)
    const unsigned short* __restrict__ mem_k,   // [H,M,D]   bf16
    const unsigned short* __restrict__ mem_v)   // [H,D,M]   bf16
{
    __shared__ unsigned short Qs[4096];   // 64x64; aliased as Ps after frag hoist
    __shared__ unsigned short Ks[8192];   // two 64-key tiles
    __shared__ unsigned short Vs[8192];   // two 64-key tiles (rows = d)
    unsigned short* Ps = Qs;

    const int t = threadIdx.x;
    const int wave = t >> 6, lane = t & 63;
    const int ln = lane & 15, lq = lane >> 4;
    const int rl = lane >> 3;
    const int cl = ((lane & 7) ^ rl) * 8;

    int bid = blockIdx.x;
    int xcd = bid & 7, rest = bid >> 3;
    int bh = xcd * 12 + (rest >> 4);
    int qt = rest & 15;
    int b = bh / 12, h = bh - b * 12;

    unsigned short* qp = qio + ((size_t)(b * TT + qt * 64)) * 768 + h * 64;
    const unsigned short* kp = k_ws + (size_t)bh * TT * 64;
    const unsigned short* vp = vT_ws + ((size_t)bh << 16);
    const unsigned short* mkp = mem_k + h * 4096;
    const unsigned short* mvp = mem_v + h * 4096;

    {
        const unsigned short* qg = qp + (size_t)(wave * 8 + rl) * 768 + cl;
        gl16(qg, &Qs[wave * 512]);
        gl16(qg + (size_t)32 * 768, &Qs[2048 + wave * 512]);
    }
    __syncthreads();
    const int e0 = (lq ^ (ln & 7)) * 8;
    const int e1 = ((lq ^ (ln & 7)) ^ 4) * 8;
    bf16x8_t aq0 = *(bf16x8_t*)&Qs[(wave * 16 + ln) * 64 + e0];
    bf16x8_t aq1 = *(bf16x8_t*)&Qs[(wave * 16 + ln) * 64 + e1];

    const unsigned short* kg = kp + (wave * 8 + rl) * 64 + cl;
    const unsigned short* vg = vp + (size_t)(wave * 8 + rl) * 1024 + cl;

    const int hi3 = ln >> 3, lo3 = ln & 7;
    const int pm = (lq & 1) << 2;
    const int pw0 = (wave * 16 + lq * 4) * 64 + lo3;

    float lsum[4] = {0.f, 0.f, 0.f, 0.f};
    f32x4_t accO[4];
    for (int nt = 0; nt < 4; nt++) accO[nt] = (f32x4_t)(0.f);

    for (int kt = 0; kt < 8; kt++) {
        __syncthreads();
        // K: keys kt*128..+128 as two 64-key tiles
        gl16(kg + kt * 8192,        &Ks[wave * 512]);
        gl16(kg + kt * 8192 + 2048, &Ks[2048 + wave * 512]);
        gl16(kg + kt * 8192 + 4096, &Ks[4096 + wave * 512]);
        gl16(kg + kt * 8192 + 6144, &Ks[6144 + wave * 512]);
        // V^T: same 128 keys (t-columns), two 64-wide tiles
        gl16(vg + kt * 128,                       &Vs[wave * 512]);
        gl16(vg + (size_t)32 * 1024 + kt * 128,      &Vs[2048 + wave * 512]);
        gl16(vg + kt * 128 + 64,                  &Vs[4096 + wave * 512]);
        gl16(vg + (size_t)32 * 1024 + kt * 128 + 64, &Vs[6144 + wave * 512]);
        __syncthreads();

        for (int half = 0; half < 2; half++) {
            const unsigned short* Kh = &Ks[half * 4096];
            const unsigned short* Vh = &Vs[half * 4096];
            f32x4_t s[4];
            for (int nt = 0; nt < 4; nt++) s[nt] = (f32x4_t)(0.f);
            for (int nt = 0; nt < 4; nt++)
                s[nt] = __builtin_amdgcn_mfma_f32_16x16x32_bf16(
                    aq0, *(bf16x8_t*)&Kh[(nt * 16 + ln) * 64 + e0], s[nt], 0, 0, 0);
            for (int nt = 0; nt < 4; nt++)
                s[nt] = __builtin_amdgcn_mfma_f32_16x16x32_bf16(
                    aq1, *(bf16x8_t*)&Kh[(nt * 16 + ln) * 64 + e1], s[nt], 0, 0, 0);

            for (int nt = 0; nt < 4; nt++) {
                for (int r = 0; r < 4; r++) {
                    float p = __builtin_amdgcn_exp2f(s[nt][r]);
                    lsum[r] += p;
                    int chp = (nt * 2 + hi3) ^ pm ^ r;
                    Ps[pw0 + r * 64 + chp * 8] = f2b_ru(p);
                }
            }
            // Ps slab is wave-private: no barrier needed
            bf16x8_t a0 = *(bf16x8_t*)&Ps[(wave * 16 + ln) * 64 + e0];
            bf16x8_t a1 = *(bf16x8_t*)&Ps[(wave * 16 + ln) * 64 + e1];
            for (int nt = 0; nt < 4; nt++) {
                accO[nt] = __builtin_amdgcn_mfma_f32_16x16x32_bf16(
                    a0, *(bf16x8_t*)&Vh[(nt * 16 + ln) * 64 + e0], accO[nt], 0, 0, 0);
                accO[nt] = __builtin_amdgcn_mfma_f32_16x16x32_bf16(
                    a1, *(bf16x8_t*)&Vh[(nt * 16 + ln) * 64 + e1], accO[nt], 0, 0, 0);
            }
        }
    }

    // memory attention: independent unnormalized softmax over 64 projected keys
    __syncthreads();
    {
        const unsigned short* mk = mkp + (wave * 8 + rl) * 64 + cl;
        const unsigned short* mv = mvp + (wave * 8 + rl) * 64 + cl;
        gl16(mk, &Ks[wave * 512]);
        gl16(mk + 2048, &Ks[2048 + wave * 512]);
        gl16(mv, &Vs[wave * 512]);
        gl16(mv + 2048, &Vs[2048 + wave * 512]);
    }
    __syncthreads();

    f32x4_t s2[4];
    for (int nt = 0; nt < 4; nt++) s2[nt] = (f32x4_t)(0.f);
    for (int nt = 0; nt < 4; nt++)
        s2[nt] = __builtin_amdgcn_mfma_f32_16x16x32_bf16(
            aq0, *(bf16x8_t*)&Ks[(nt * 16 + ln) * 64 + e0], s2[nt], 0, 0, 0);
    for (int nt = 0; nt < 4; nt++)
        s2[nt] = __builtin_amdgcn_mfma_f32_16x16x32_bf16(
            aq1, *(bf16x8_t*)&Ks[(nt * 16 + ln) * 64 + e1], s2[nt], 0, 0, 0);

    float l2[4] = {0.f, 0.f, 0.f, 0.f};
    for (int nt = 0; nt < 4; nt++) {
        for (int r = 0; r < 4; r++) {
            float p = __builtin_amdgcn_exp2f(s2[nt][r]);
            l2[r] += p;
            int chp = (nt * 2 + hi3) ^ pm ^ r;
            Ps[pw0 + r * 64 + chp * 8] = f2b_ru(p);
        }
    }
    f32x4_t accM[4];
    for (int nt = 0; nt < 4; nt++) accM[nt] = (f32x4_t)(0.f);
    {
        bf16x8_t a0 = *(bf16x8_t*)&Ps[(wave * 16 + ln) * 64 + e0];
        bf16x8_t a1 = *(bf16x8_t*)&Ps[(wave * 16 + ln) * 64 + e1];
        for (int nt = 0; nt < 4; nt++) {
            accM[nt] = __builtin_amdgcn_mfma_f32_16x16x32_bf16(
                a0, *(bf16x8_t*)&Vs[(nt * 16 + ln) * 64 + e0], accM[nt], 0, 0, 0);
            accM[nt] = __builtin_amdgcn_mfma_f32_16x16x32_bf16(
                a1, *(bf16x8_t*)&Vs[(nt * 16 + ln) * 64 + e1], accM[nt], 0, 0, 0);
        }
    }

    float inv[4], inv2[4];
    for (int r = 0; r < 4; r++) {
        float a = lsum[r], c = l2[r];
        a += __shfl_xor(a, 1); a += __shfl_xor(a, 2);
        a += __shfl_xor(a, 4); a += __shfl_xor(a, 8);
        c += __shfl_xor(c, 1); c += __shfl_xor(c, 2);
        c += __shfl_xor(c, 4); c += __shfl_xor(c, 8);
        inv[r] = 1.f / a;
        inv2[r] = 1.f / c;
    }

    for (int nt = 0; nt < 4; nt++) {
        for (int r = 0; r < 4; r++) {
            int lrow = wave * 16 + lq * 4 + r;
            int lcol = nt * 16 + ln;
            float val = accO[nt][r] * inv[r] + accM[nt][r] * inv2[r];
            qp[(size_t)lrow * 768 + lcol] = f2b(val);
        }
    }
}

// ---------------- host ----------------
extern "C" void kernel_launch(void* const* d_in, const int* in_sizes, int n_in,
                              void* d_out, int out_size, void* d_ws, size_t ws_size,
                              hipStream_t stream) {
    const float* x      = (const float*)d_in[0];
    const float* w_qkv  = (const float*)d_in[1];
    const float* b_qkv  = (const float*)d_in[2];
    const float* w_out  = (const float*)d_in[3];
    const float* b_out  = (const float*)d_in[4];
    const float* w_mem  = (const float*)d_in[5];
    const float* b_mem  = (const float*)d_in[6];
    const float* memory = (const float*)d_in[7];

    unsigned short* ws = (unsigned short*)d_ws;
    unsigned short* q_ws   = ws;                         // [B,T,C] bf16; attn in-place
    unsigned short* k_ws   = ws + (size_t)QSZ;           // [B,H,T,D]; v at +QSZ
    unsigned short* woutT  = ws + 3 * (size_t)QSZ;       // [768][768] bf16 (N x K)
    unsigned short* mem_k  = woutT + (size_t)EMBED * EMBED;
    unsigned short* mem_v  = mem_k + (size_t)NH * MEMN * HD;

    unsigned short* xb    = (unsigned short*)d_out;      // [8192][768] bf16
    unsigned short* wqkvT = xb + (size_t)QSZ;            // [2304][768] bf16
    unsigned short* vT    = (unsigned short*)d_out;      // [B,H,D,T] bf16

    // 1) fused prep (cvt + 2 tcvt + memproj)
    prep_kernel<<<PREP_TOTAL, 256, 0, stream>>>(
        x, w_qkv, w_out, memory, w_mem, b_mem, xb, wqkvT, woutT, mem_k, mem_v);

    // 2) QKV projection: q (pre-scaled) -> q_ws; k,v -> [B,H,T,D]
    gemm_bt<<<dim3(QKV_N / 128, ROWS / 128), 256, 0, stream>>>(
        xb, wqkvT, b_qkv, q_ws, k_ws, nullptr, ROWS, QKV_N, EMBED, 0);

    // 3) transpose v -> vT [B,H,D,T]
    vtrans_kernel<<<dim3(TT / 64, BB * NH), 256, 0, stream>>>(k_ws + (size_t)QSZ, vT);

    // 4) attention (local flash + memory), in-place over q_ws
    attn_kernel<<<16 * NH * BB, 256, 0, stream>>>(q_ws, k_ws, vT, mem_k, mem_v);

    // 5) output projection: q_ws(bf16) @ w_out + b_out -> d_out fp32
    gemm_bt<<<dim3(EMBED / 128, ROWS / 128), 256, 0, stream>>>(
        q_ws, woutT, b_out, nullptr, nullptr, (float*)d_out, ROWS, EMBED, EMBED, 1);
}

// Round 11
// 241.183 us; speedup vs baseline: 2.7314x; 1.0552x over previous
//
#include <hip/hip_runtime.h>

#define EMBED 768
#define NH 12
#define HD 64
#define MEMN 64
#define BB 8
#define TT 1024
#define ROWS 8192
#define QKV_N 2304
#define QSZ 6291456           // B*T*C = B*NH*TT*HD (elements)

typedef short bf16x8_t __attribute__((ext_vector_type(8)));
typedef float f32x4_t __attribute__((ext_vector_type(4)));

__device__ __forceinline__ unsigned short f2b(float f){
    union { float f; unsigned int i; } v; v.f = f;
    unsigned int x = v.i;
    unsigned int r = x + 0x7fffu + ((x >> 16) & 1u);
    return (unsigned short)(r >> 16);
}
// round-half-up convert for non-negative values (softmax p)
__device__ __forceinline__ unsigned short f2b_ru(float f){
    union { float f; unsigned int i; } v; v.f = f;
    return (unsigned short)((v.i + 0x8000u) >> 16);
}

// async global->LDS, 16B per lane; lds base must be wave-uniform (lane*16 implicit)
__device__ __forceinline__ void gl16(const unsigned short* g, unsigned short* l){
    __builtin_amdgcn_global_load_lds(
        (const __attribute__((address_space(1))) void*)g,
        (__attribute__((address_space(3))) void*)l,
        16, 0, 0);
}

// ---- fused prep: x cvt + w_qkv tcvt + w_out tcvt + memproj (one graph node) ----
#define PREP_CVT   3072
#define PREP_TQKV  4800
#define PREP_TOUT  5376
#define PREP_TOTAL 5388

__global__ __launch_bounds__(256) void prep_kernel(
    const float* __restrict__ x,
    const float* __restrict__ w_qkv,
    const float* __restrict__ w_out,
    const float* __restrict__ memory,
    const float* __restrict__ w_mem,
    const float* __restrict__ b_mem,
    unsigned short* __restrict__ xb,
    unsigned short* __restrict__ wqkvT,
    unsigned short* __restrict__ woutT,
    unsigned short* __restrict__ mem_k,
    unsigned short* __restrict__ mem_v)
{
    __shared__ unsigned short pool[5120];
    const int bid = blockIdx.x;
    const int t = threadIdx.x;

    if (bid < PREP_CVT) {
        int i = bid * 2048 + t * 8;
        float4 f0 = *(const float4*)&x[i];
        float4 f1 = *(const float4*)&x[i + 4];
        union { bf16x8_t v; unsigned short s[8]; } u;
        u.s[0] = f2b(f0.x); u.s[1] = f2b(f0.y); u.s[2] = f2b(f0.z); u.s[3] = f2b(f0.w);
        u.s[4] = f2b(f1.x); u.s[5] = f2b(f1.y); u.s[6] = f2b(f1.z); u.s[7] = f2b(f1.w);
        *(bf16x8_t*)&xb[i] = u.v;
    } else if (bid < PREP_TOUT) {
        const float* in; unsigned short* out; int R, C, loc;
        if (bid < PREP_TQKV) { in = w_qkv; out = wqkvT; R = EMBED; C = QKV_N; loc = bid - PREP_CVT; }
        else                 { in = w_out; out = woutT; R = EMBED; C = EMBED; loc = bid - PREP_TQKV; }
        int nbc = C / 32;
        int bc = (loc % nbc) * 32, br = (loc / nbc) * 32;
        unsigned short (*tile)[33] = (unsigned short(*)[33])pool;
        int lr = t >> 5, lc = t & 31;
        for (int i = 0; i < 4; i++) {
            int r = lr + i * 8;
            tile[r][lc] = f2b(in[(size_t)(br + r) * C + bc + lc]);
        }
        __syncthreads();
        for (int i = 0; i < 4; i++) {
            int r = lr + i * 8;
            out[(size_t)(bc + r) * R + br + lc] = tile[lc][r];
        }
    } else {
        unsigned short (*As)[40] = (unsigned short(*)[40])pool;
        unsigned short (*Bs)[40] = (unsigned short(*)[40])(pool + 2560);
        int wave = t >> 6, lane = t & 63;
        int ln = lane & 15, lq = lane >> 4;
        int bn = (bid - PREP_TOUT) * 64;
        const int K = EMBED, N = EMBED;

        f32x4_t acc[4];
        for (int i = 0; i < 4; i++) acc[i] = (f32x4_t)(0.f);
        int sm = t >> 2, sk = (t & 3) * 8;
        int bk = t >> 3, bn8 = (t & 7) * 8;

        for (int k0 = 0; k0 < K; k0 += 32) {
            __syncthreads();
            {
                float4 f0 = *(const float4*)&memory[(size_t)sm * K + k0 + sk];
                float4 f1 = *(const float4*)&memory[(size_t)sm * K + k0 + sk + 4];
                unsigned short* ap = &As[sm][sk];
                ap[0] = f2b(f0.x); ap[1] = f2b(f0.y); ap[2] = f2b(f0.z); ap[3] = f2b(f0.w);
                ap[4] = f2b(f1.x); ap[5] = f2b(f1.y); ap[6] = f2b(f1.z); ap[7] = f2b(f1.w);
            }
            {
                float4 g0 = *(const float4*)&w_mem[(size_t)(k0 + bk) * N + bn + bn8];
                float4 g1 = *(const float4*)&w_mem[(size_t)(k0 + bk) * N + bn + bn8 + 4];
                Bs[bn8 + 0][bk] = f2b(g0.x); Bs[bn8 + 1][bk] = f2b(g0.y);
                Bs[bn8 + 2][bk] = f2b(g0.z); Bs[bn8 + 3][bk] = f2b(g0.w);
                Bs[bn8 + 4][bk] = f2b(g1.x); Bs[bn8 + 5][bk] = f2b(g1.y);
                Bs[bn8 + 6][bk] = f2b(g1.z); Bs[bn8 + 7][bk] = f2b(g1.w);
            }
            __syncthreads();
            bf16x8_t a = *(bf16x8_t*)&As[wave * 16 + ln][lq * 8];
            for (int nt = 0; nt < 4; nt++) {
                bf16x8_t bf = *(bf16x8_t*)&Bs[nt * 16 + ln][lq * 8];
                acc[nt] = __builtin_amdgcn_mfma_f32_16x16x32_bf16(a, bf, acc[nt], 0, 0, 0);
            }
        }
        for (int nt = 0; nt < 4; nt++) {
            int c = bn + nt * 16 + ln;
            float bv = b_mem[c];
            for (int r = 0; r < 4; r++) {
                int row = wave * 16 + lq * 4 + r;
                int h = c >> 6, d = c & 63;
                unsigned short o = f2b(acc[nt][r] + bv);
                mem_k[((h * 64 + row) << 6) + d] = o;   // [H,M,D]
                mem_v[((h * 64 + d) << 6) + row] = o;   // [H,D,M]
            }
        }
    }
}

// ---- bf16 [BH][T][D] -> [BH][D][T] transpose, coalesced both sides ----
__global__ __launch_bounds__(256) void vtrans_kernel(
    const unsigned short* __restrict__ in, unsigned short* __restrict__ out)
{
    __shared__ unsigned short tile[64][72];
    int t0 = blockIdx.x * 64;
    int bh = blockIdx.y;
    const unsigned short* ip = in + ((size_t)bh * TT + t0) * 64;
    unsigned short* op = out + ((size_t)bh * 64) * TT + t0;
    int t = threadIdx.x;
    for (int i = 0; i < 2; i++) {
        int idx = i * 256 + t;
        int r = idx >> 3, c8 = (idx & 7) * 8;
        *(bf16x8_t*)&tile[r][c8] = *(const bf16x8_t*)&ip[(size_t)r * 64 + c8];
    }
    __syncthreads();
    for (int i = 0; i < 2; i++) {
        int idx = i * 256 + t;
        int d = idx >> 3, tc8 = (idx & 7) * 8;
        union { bf16x8_t v; unsigned short s[8]; } u;
        for (int j = 0; j < 8; j++) u.s[j] = tile[tc8 + j][d];
        *(bf16x8_t*)&op[(size_t)d * TT + tc8] = u.v;
    }
}

// ---- 256x128 bf16 GEMM, 512 threads (8 waves x 64x64 quadrant), BK=64,
// XOR-swizzled LDS. Halves per-CU barrier epochs vs the 128x128/4-wave shape —
// the K=768 loop is barrier-drain-bound (r10: ~3800 cyc/epoch vs 155 cyc MFMA). ----
__global__ __launch_bounds__(512) void gemm512(
    const unsigned short* __restrict__ A,
    const unsigned short* __restrict__ BT,
    const float* __restrict__ bias,
    unsigned short* __restrict__ dq,
    unsigned short* __restrict__ dkv,
    int M, int N, int K)
{
    __shared__ unsigned short As[16384];  // 256 x 64
    __shared__ unsigned short Bs[8192];   // 128 x 64
    const int t = threadIdx.x;
    const int wave = t >> 6, lane = t & 63;
    const int ln = lane & 15, lq = lane >> 4;
    const int wm = (wave >> 1) * 64, wn = (wave & 1) * 64;
    const int bm = blockIdx.y * 256, bn = blockIdx.x * 128;

    f32x4_t acc[4][4];
    for (int i = 0; i < 4; i++)
        for (int j = 0; j < 4; j++) acc[i][j] = (f32x4_t)(0.f);

    const int rl8 = lane >> 3;
    const int swz = ((lane & 7) ^ rl8) * 8;
    const unsigned short* Ap = A + (size_t)(bm + wave * 32 + rl8) * K + swz;
    const unsigned short* Bp = BT + (size_t)(bn + wave * 16 + rl8) * K + swz;
    unsigned short* asd = &As[wave * 2048];
    unsigned short* bsd = &Bs[wave * 1024];

    const int e0 = (lq ^ (ln & 7)) * 8;
    const int e1 = e0 ^ 32;

    for (int k0 = 0; k0 < K; k0 += 64) {
        __syncthreads();
        for (int i = 0; i < 4; i++)
            gl16(Ap + (size_t)(i * 8) * K + k0, asd + i * 512);
        for (int i = 0; i < 2; i++)
            gl16(Bp + (size_t)(i * 8) * K + k0, bsd + i * 512);
        __syncthreads();

        {
            bf16x8_t af[4], bfr[4];
            for (int mt = 0; mt < 4; mt++)
                af[mt] = *(bf16x8_t*)&As[(wm + mt * 16 + ln) * 64 + e0];
            for (int nt = 0; nt < 4; nt++)
                bfr[nt] = *(bf16x8_t*)&Bs[(wn + nt * 16 + ln) * 64 + e0];
            for (int mt = 0; mt < 4; mt++)
                for (int nt = 0; nt < 4; nt++)
                    acc[mt][nt] = __builtin_amdgcn_mfma_f32_16x16x32_bf16(
                        af[mt], bfr[nt], acc[mt][nt], 0, 0, 0);
        }
        {
            bf16x8_t af[4], bfr[4];
            for (int mt = 0; mt < 4; mt++)
                af[mt] = *(bf16x8_t*)&As[(wm + mt * 16 + ln) * 64 + e1];
            for (int nt = 0; nt < 4; nt++)
                bfr[nt] = *(bf16x8_t*)&Bs[(wn + nt * 16 + ln) * 64 + e1];
            for (int mt = 0; mt < 4; mt++)
                for (int nt = 0; nt < 4; nt++)
                    acc[mt][nt] = __builtin_amdgcn_mfma_f32_16x16x32_bf16(
                        af[mt], bfr[nt], acc[mt][nt], 0, 0, 0);
        }
    }

    const float QSCALE = 0.125f * 1.44269504088896340736f;
    const int s = bn / 768;          // block-uniform: 768 % 128 == 0
    for (int nt = 0; nt < 4; nt++) {
        int c = bn + wn + nt * 16 + ln;
        int rem = c - s * 768;
        int h = rem >> 6, d = rem & 63;
        float bv = bias[c];
        for (int mt = 0; mt < 4; mt++) {
            for (int r = 0; r < 4; r++) {
                int row = bm + wm + mt * 16 + lq * 4 + r;
                float val = acc[mt][nt][r] + bv;
                if (s == 0) {
                    dq[(size_t)row * 768 + rem] = f2b(val * QSCALE);
                } else {
                    int bb = row >> 10, tt = row & 1023;
                    dkv[(size_t)(s - 1) * QSZ +
                        (((size_t)(bb * 12 + h) * 1024 + tt) << 6) + d] = f2b(val);
                }
            }
        }
    }
}

// ---- 128x128 bf16 GEMM, BK=64, XOR-swizzled (kept for out-proj: 384 blocks) ----
__global__ __launch_bounds__(256) void gemm_bt(
    const unsigned short* __restrict__ A,
    const unsigned short* __restrict__ BT,
    const float* __restrict__ bias,
    float* __restrict__ df,
    int M, int N, int K)
{
    __shared__ unsigned short As[8192];   // 128 x 64
    __shared__ unsigned short Bs[8192];
    const int t = threadIdx.x;
    const int wave = t >> 6, lane = t & 63;
    const int ln = lane & 15, lq = lane >> 4;
    const int wm = (wave >> 1) * 64, wn = (wave & 1) * 64;
    const int bm = blockIdx.y * 128, bn = blockIdx.x * 128;

    f32x4_t acc[4][4];
    for (int i = 0; i < 4; i++)
        for (int j = 0; j < 4; j++) acc[i][j] = (f32x4_t)(0.f);

    const int rl8 = lane >> 3;
    const int swz = ((lane & 7) ^ rl8) * 8;
    const unsigned short* Ap = A + (size_t)(bm + wave * 32 + rl8) * K + swz;
    const unsigned short* Bp = BT + (size_t)(bn + wave * 32 + rl8) * K + swz;
    unsigned short* asd = &As[wave * 2048];
    unsigned short* bsd = &Bs[wave * 2048];

    const int e0 = (lq ^ (ln & 7)) * 8;
    const int e1 = e0 ^ 32;

    for (int k0 = 0; k0 < K; k0 += 64) {
        __syncthreads();
        for (int i = 0; i < 4; i++) {
            gl16(Ap + (size_t)(i * 8) * K + k0, asd + i * 512);
            gl16(Bp + (size_t)(i * 8) * K + k0, bsd + i * 512);
        }
        __syncthreads();

        {
            bf16x8_t af[4], bfr[4];
            for (int mt = 0; mt < 4; mt++)
                af[mt] = *(bf16x8_t*)&As[(wm + mt * 16 + ln) * 64 + e0];
            for (int nt = 0; nt < 4; nt++)
                bfr[nt] = *(bf16x8_t*)&Bs[(wn + nt * 16 + ln) * 64 + e0];
            for (int mt = 0; mt < 4; mt++)
                for (int nt = 0; nt < 4; nt++)
                    acc[mt][nt] = __builtin_amdgcn_mfma_f32_16x16x32_bf16(
                        af[mt], bfr[nt], acc[mt][nt], 0, 0, 0);
        }
        {
            bf16x8_t af[4], bfr[4];
            for (int mt = 0; mt < 4; mt++)
                af[mt] = *(bf16x8_t*)&As[(wm + mt * 16 + ln) * 64 + e1];
            for (int nt = 0; nt < 4; nt++)
                bfr[nt] = *(bf16x8_t*)&Bs[(wn + nt * 16 + ln) * 64 + e1];
            for (int mt = 0; mt < 4; mt++)
                for (int nt = 0; nt < 4; nt++)
                    acc[mt][nt] = __builtin_amdgcn_mfma_f32_16x16x32_bf16(
                        af[mt], bfr[nt], acc[mt][nt], 0, 0, 0);
        }
    }

    for (int nt = 0; nt < 4; nt++) {
        int c = bn + wn + nt * 16 + ln;
        float bv = bias[c];
        for (int mt = 0; mt < 4; mt++)
            for (int r = 0; r < 4; r++) {
                int row = bm + wm + mt * 16 + lq * 4 + r;
                df[(size_t)row * N + c] = acc[mt][nt][r] + bv;
            }
    }
}

// ---- flash attention: 512 threads, 128 q-rows/block (8 waves x 16 q-rows),
// 128-key kt steps, unnormalized exp2 (scale folded into q), XOR-swizzled LDS. ----
__global__ __launch_bounds__(512) void attn_kernel(
    unsigned short* __restrict__ qio,           // [B,T,768] bf16, in/out (q pre-scaled)
    const unsigned short* __restrict__ k_ws,    // [B,H,T,D] bf16
    const unsigned short* __restrict__ vT_ws,   // [B,H,D,T] bf16 (transposed)
    const unsigned short* __restrict__ mem_k,   // [H,M,D]   bf16
    const unsigned short* __restrict__ mem_v)   // [H,D,M]   bf16
{
    __shared__ unsigned short Qs[8192];   // 128x64; aliased as Ps after frag hoist
    __shared__ unsigned short Ks[8192];   // two 64-key tiles
    __shared__ unsigned short Vs[8192];   // two 64-key tiles (rows = d)
    unsigned short* Ps = Qs;

    const int t = threadIdx.x;
    const int wave = t >> 6, lane = t & 63;
    const int ln = lane & 15, lq = lane >> 4;
    const int rl = lane >> 3;
    const int cl = ((lane & 7) ^ rl) * 8;

    // XCD swizzle: 8 q-tiles of one (b,h) land on one XCD
    int bid = blockIdx.x;
    int xcd = bid & 7, rest = bid >> 3;        // rest 0..95
    int bh = xcd * 12 + (rest >> 3);           // 0..95 == b*NH + h
    int qt = rest & 7;                         // 0..7 (128-row q tiles)
    int b = bh / 12, h = bh - b * 12;

    unsigned short* qp = qio + ((size_t)(b * TT + qt * 128)) * 768 + h * 64;
    const unsigned short* kp = k_ws + (size_t)bh * TT * 64;
    const unsigned short* vp = vT_ws + ((size_t)bh << 16);
    const unsigned short* mkp = mem_k + h * 4096;
    const unsigned short* mvp = mem_v + h * 4096;

    // stage Q (2 slabs per wave), hoist this wave's A-fragments (16 q-rows)
    {
        const unsigned short* qg = qp + (size_t)(wave * 16 + rl) * 768 + cl;
        gl16(qg, &Qs[wave * 1024]);
        gl16(qg + (size_t)8 * 768, &Qs[wave * 1024 + 512]);
    }
    __syncthreads();
    const int e0 = (lq ^ (ln & 7)) * 8;
    const int e1 = ((lq ^ (ln & 7)) ^ 4) * 8;
    bf16x8_t aq0 = *(bf16x8_t*)&Qs[(wave * 16 + ln) * 64 + e0];
    bf16x8_t aq1 = *(bf16x8_t*)&Qs[(wave * 16 + ln) * 64 + e1];

    // staging bases: K slabs s=w*2+i (keys s*8..+8); V slabs: half=s>>3, d-rows (s&7)*8..+8
    const unsigned short* kg = kp + (wave * 16 + rl) * 64 + cl;
    const unsigned short* vg = vp + (size_t)((wave & 3) * 16 + rl) * 1024 + (wave >> 2) * 64 + cl;

    const int hi3 = ln >> 3, lo3 = ln & 7;
    const int pm = (lq & 1) << 2;
    const int pw0 = (wave * 16 + lq * 4) * 64 + lo3;

    float lsum[4] = {0.f, 0.f, 0.f, 0.f};
    f32x4_t accO[4];
    for (int nt = 0; nt < 4; nt++) accO[nt] = (f32x4_t)(0.f);

    for (int kt = 0; kt < 8; kt++) {
        __syncthreads();
        gl16(kg + kt * 8192,        &Ks[wave * 1024]);
        gl16(kg + kt * 8192 + 512,  &Ks[wave * 1024 + 512]);
        gl16(vg + kt * 128,                 &Vs[wave * 1024]);
        gl16(vg + (size_t)8 * 1024 + kt * 128, &Vs[wave * 1024 + 512]);
        __syncthreads();

        for (int half = 0; half < 2; half++) {
            const unsigned short* Kh = &Ks[half * 4096];
            const unsigned short* Vh = &Vs[half * 4096];
            f32x4_t s[4];
            for (int nt = 0; nt < 4; nt++) s[nt] = (f32x4_t)(0.f);
            for (int nt = 0; nt < 4; nt++)
                s[nt] = __builtin_amdgcn_mfma_f32_16x16x32_bf16(
                    aq0, *(bf16x8_t*)&Kh[(nt * 16 + ln) * 64 + e0], s[nt], 0, 0, 0);
            for (int nt = 0; nt < 4; nt++)
                s[nt] = __builtin_amdgcn_mfma_f32_16x16x32_bf16(
                    aq1, *(bf16x8_t*)&Kh[(nt * 16 + ln) * 64 + e1], s[nt], 0, 0, 0);

            for (int nt = 0; nt < 4; nt++) {
                for (int r = 0; r < 4; r++) {
                    float p = __builtin_amdgcn_exp2f(s[nt][r]);
                    lsum[r] += p;
                    int chp = (nt * 2 + hi3) ^ pm ^ r;
                    Ps[pw0 + r * 64 + chp * 8] = f2b_ru(p);
                }
            }
            // Ps slab is wave-private: no barrier needed
            bf16x8_t a0 = *(bf16x8_t*)&Ps[(wave * 16 + ln) * 64 + e0];
            bf16x8_t a1 = *(bf16x8_t*)&Ps[(wave * 16 + ln) * 64 + e1];
            for (int nt = 0; nt < 4; nt++) {
                accO[nt] = __builtin_amdgcn_mfma_f32_16x16x32_bf16(
                    a0, *(bf16x8_t*)&Vh[(nt * 16 + ln) * 64 + e0], accO[nt], 0, 0, 0);
                accO[nt] = __builtin_amdgcn_mfma_f32_16x16x32_bf16(
                    a1, *(bf16x8_t*)&Vh[(nt * 16 + ln) * 64 + e1], accO[nt], 0, 0, 0);
            }
        }
    }

    // memory attention: 64 projected keys (each wave stages 1 slab of K and V)
    __syncthreads();
    gl16(mkp + (wave * 8 + rl) * 64 + cl, &Ks[wave * 512]);
    gl16(mvp + (wave * 8 + rl) * 64 + cl, &Vs[wave * 512]);
    __syncthreads();

    f32x4_t s2[4];
    for (int nt = 0; nt < 4; nt++) s2[nt] = (f32x4_t)(0.f);
    for (int nt = 0; nt < 4; nt++)
        s2[nt] = __builtin_amdgcn_mfma_f32_16x16x32_bf16(
            aq0, *(bf16x8_t*)&Ks[(nt * 16 + ln) * 64 + e0], s2[nt], 0, 0, 0);
    for (int nt = 0; nt < 4; nt++)
        s2[nt] = __builtin_amdgcn_mfma_f32_16x16x32_bf16(
            aq1, *(bf16x8_t*)&Ks[(nt * 16 + ln) * 64 + e1], s2[nt], 0, 0, 0);

    float l2[4] = {0.f, 0.f, 0.f, 0.f};
    for (int nt = 0; nt < 4; nt++) {
        for (int r = 0; r < 4; r++) {
            float p = __builtin_amdgcn_exp2f(s2[nt][r]);
            l2[r] += p;
            int chp = (nt * 2 + hi3) ^ pm ^ r;
            Ps[pw0 + r * 64 + chp * 8] = f2b_ru(p);
        }
    }
    f32x4_t accM[4];
    for (int nt = 0; nt < 4; nt++) accM[nt] = (f32x4_t)(0.f);
    {
        bf16x8_t a0 = *(bf16x8_t*)&Ps[(wave * 16 + ln) * 64 + e0];
        bf16x8_t a1 = *(bf16x8_t*)&Ps[(wave * 16 + ln) * 64 + e1];
        for (int nt = 0; nt < 4; nt++) {
            accM[nt] = __builtin_amdgcn_mfma_f32_16x16x32_bf16(
                a0, *(bf16x8_t*)&Vs[(nt * 16 + ln) * 64 + e0], accM[nt], 0, 0, 0);
            accM[nt] = __builtin_amdgcn_mfma_f32_16x16x32_bf16(
                a1, *(bf16x8_t*)&Vs[(nt * 16 + ln) * 64 + e1], accM[nt], 0, 0, 0);
        }
    }

    float inv[4], inv2[4];
    for (int r = 0; r < 4; r++) {
        float a = lsum[r], c = l2[r];
        a += __shfl_xor(a, 1); a += __shfl_xor(a, 2);
        a += __shfl_xor(a, 4); a += __shfl_xor(a, 8);
        c += __shfl_xor(c, 1); c += __shfl_xor(c, 2);
        c += __shfl_xor(c, 4); c += __shfl_xor(c, 8);
        inv[r] = 1.f / a;
        inv2[r] = 1.f / c;
    }

    for (int nt = 0; nt < 4; nt++) {
        for (int r = 0; r < 4; r++) {
            int lrow = wave * 16 + lq * 4 + r;
            int lcol = nt * 16 + ln;
            float val = accO[nt][r] * inv[r] + accM[nt][r] * inv2[r];
            qp[(size_t)lrow * 768 + lcol] = f2b(val);
        }
    }
}

// ---------------- host ----------------
extern "C" void kernel_launch(void* const* d_in, const int* in_sizes, int n_in,
                              void* d_out, int out_size, void* d_ws, size_t ws_size,
                              hipStream_t stream) {
    const float* x      = (const float*)d_in[0];
    const float* w_qkv  = (const float*)d_in[1];
    const float* b_qkv  = (const float*)d_in[2];
    const float* w_out  = (const float*)d_in[3];
    const float* b_out  = (const float*)d_in[4];
    const float* w_mem  = (const float*)d_in[5];
    const float* b_mem  = (const float*)d_in[6];
    const float* memory = (const float*)d_in[7];

    unsigned short* ws = (unsigned short*)d_ws;
    unsigned short* q_ws   = ws;                         // [B,T,C] bf16; attn in-place
    unsigned short* k_ws   = ws + (size_t)QSZ;           // [B,H,T,D]; v at +QSZ
    unsigned short* woutT  = ws + 3 * (size_t)QSZ;       // [768][768] bf16 (N x K)
    unsigned short* mem_k  = woutT + (size_t)EMBED * EMBED;
    unsigned short* mem_v  = mem_k + (size_t)NH * MEMN * HD;

    unsigned short* xb    = (unsigned short*)d_out;      // [8192][768] bf16
    unsigned short* wqkvT = xb + (size_t)QSZ;            // [2304][768] bf16
    unsigned short* vT    = (unsigned short*)d_out;      // [B,H,D,T] bf16

    // 1) fused prep (cvt + 2 tcvt + memproj)
    prep_kernel<<<PREP_TOTAL, 256, 0, stream>>>(
        x, w_qkv, w_out, memory, w_mem, b_mem, xb, wqkvT, woutT, mem_k, mem_v);

    // 2) QKV projection (512-thread 256x128 tiles): q -> q_ws; k,v -> [B,H,T,D]
    gemm512<<<dim3(QKV_N / 128, ROWS / 256), 512, 0, stream>>>(
        xb, wqkvT, b_qkv, q_ws, k_ws, ROWS, QKV_N, EMBED);

    // 3) transpose v -> vT [B,H,D,T]
    vtrans_kernel<<<dim3(TT / 64, BB * NH), 256, 0, stream>>>(k_ws + (size_t)QSZ, vT);

    // 4) attention (local flash + memory), in-place over q_ws; 768 blocks x 512 thr
    attn_kernel<<<8 * NH * BB, 512, 0, stream>>>(q_ws, k_ws, vT, mem_k, mem_v);

    // 5) output projection: q_ws(bf16) @ w_out + b_out -> d_out fp32
    gemm_bt<<<dim3(EMBED / 128, ROWS / 128), 256, 0, stream>>>(
        q_ws, woutT, b_out, (float*)d_out, ROWS, EMBED, EMBED);
}